// Round 10
// baseline (345.111 us; speedup 1.0000x reference)
//
#include <hip/hip_runtime.h>
#include <math.h>

#define H 128
#define NNODE 50000
#define NEDGE 800000
#define NBLK16 3125      // NNODE / 16
#define NBUK 782         // buckets of 64 dst nodes: ceil(50000/64)
#define BCH 256          // edge chunks per type
#define CHUNK 3125       // NEDGE / BCH
#define SCANH_N 200192   // NBUK * BCH
#define NBS 196          // scan blocks per array (1024 elems each)
#define BCAP 1536        // max edges per bucket (mean 1024)
#define GBLK 12500       // gather blocks per direction (4 rows/block, 1 row/wave)
#define SAGEB 782        // sage blocks per direction (64 rows/block)

typedef unsigned short ushortT;
typedef unsigned int uintT;
typedef __attribute__((ext_vector_type(8))) short short8;
typedef __attribute__((ext_vector_type(4))) float floatx4;
typedef __attribute__((ext_vector_type(2))) float float2v;

static __device__ __forceinline__ float bf2f(ushortT u) {
    union { uintT i; float f; } c; c.i = ((uintT)u) << 16; return c.f;
}
static __device__ __forceinline__ ushortT f2bf(float f) {
    union { float f; uintT i; } c; c.f = f;
    uintT lsb = (c.i >> 16) & 1;
    c.i += 0x7fffu + lsb;          // round-to-nearest-even
    return (ushortT)(c.i >> 16);
}
static __device__ __forceinline__ float lo2f(uintT v) {
    union { uintT i; float f; } c; c.i = v << 16; return c.f;
}
static __device__ __forceinline__ float hi2f(uintT v) {
    union { uintT i; float f; } c; c.i = v & 0xffff0000u; return c.f;
}
static __device__ __forceinline__ uintT pack2(float a, float b) {
    return (uintT)f2bf(a) | ((uintT)f2bf(b) << 16);
}
static __device__ __forceinline__ float2v up2(uintT v) {
    return (float2v){lo2f(v), hi2f(v)};
}

// ---------------------------------------------------------------------------
// D1: weight convert+transpose (blocks 0..591) + edge histograms (592..1103)
// wT offsets: HxH mat m at m*16384; enc_user 131072; enc_item 139264; w1 143360
// scanH layout: [bucket][chunk] flattened -> index b*BCH + c
// ---------------------------------------------------------------------------
__global__ void setup_kernel(const float* __restrict__ s0, const float* __restrict__ s1,
                             const float* __restrict__ s2, const float* __restrict__ s3,
                             const float* __restrict__ s4, const float* __restrict__ s5,
                             const float* __restrict__ s6, const float* __restrict__ s7,
                             const float* __restrict__ seu, const float* __restrict__ sei,
                             const float* __restrict__ sw1, ushortT* __restrict__ wT,
                             const int* __restrict__ e0, const int* __restrict__ e1,
                             int* __restrict__ scanH0, int* __restrict__ scanH1) {
    __shared__ int hist[NBUK];
    const int b = blockIdx.x, t = threadIdx.x;
    if (b < 512) {
        const int m = b >> 6;
        const float* s = (m == 0) ? s0 : (m == 1) ? s1 : (m == 2) ? s2 : (m == 3) ? s3
                       : (m == 4) ? s4 : (m == 5) ? s5 : (m == 6) ? s6 : s7;
        int i = (b & 63) * 256 + t;
        int k = i >> 7, c = i & 127;
        wT[m * 16384 + c * 128 + k] = f2bf(s[k * 128 + c]);
    } else if (b < 544) {
        int i = (b - 512) * 256 + t;
        int k = i >> 7, c = i & 127;
        wT[131072 + c * 64 + k] = f2bf(seu[k * 128 + c]);
    } else if (b < 560) {
        int i = (b - 544) * 256 + t;
        int k = i >> 7, c = i & 127;
        wT[139264 + c * 32 + k] = f2bf(sei[k * 128 + c]);
    } else if (b < 592) {
        int i = (b - 560) * 256 + t;
        int k = i >> 6, c = i & 63;
        wT[143360 + c * 128 + k] = f2bf(sw1[k * 64 + c]);
    } else {
        const int hb = b - 592;
        const bool first = hb < BCH;
        const int c = first ? hb : hb - BCH;
        const int* edst = (first ? e0 : e1) + NEDGE + c * CHUNK;
        int* scanH = first ? scanH0 : scanH1;
        for (int i = t; i < NBUK; i += 256) hist[i] = 0;
        __syncthreads();
        for (int e = t; e < CHUNK; e += 256) atomicAdd(&hist[edst[e] >> 6], 1);
        __syncthreads();
        for (int i = t; i < NBUK; i += 256) scanH[i * BCH + c] = hist[i];
    }
}

// ---------------------------------------------------------------------------
// D2: merged encoders (MFMA, blocks [0,6250)) + scanH exclusive scans (rest)
// ---------------------------------------------------------------------------
__global__ void encscan_kernel(const float* __restrict__ xu, const ushortT* __restrict__ wTu,
                               const float* __restrict__ bu,
                               const float* __restrict__ xi, const ushortT* __restrict__ wTi,
                               const float* __restrict__ bi,
                               ushortT* __restrict__ outu, ushortT* __restrict__ outi,
                               int* __restrict__ scanH0, int* __restrict__ bsum0,
                               int* __restrict__ scanH1, int* __restrict__ bsum1) {
    __shared__ ushortT xs[16 * 72];
    __shared__ int tmp[256];
    const int tx = threadIdx.x;
    if (blockIdx.x >= 2 * NBLK16) {
        // ---- exclusive scan over SCANH_N, in place; bsum = raw block sums
        const int sb = blockIdx.x - 2 * NBLK16;
        const bool first = sb < NBS;
        const int blk = first ? sb : sb - NBS;
        int* arr = first ? scanH0 : scanH1;
        int* bsum = first ? bsum0 : bsum1;
        const int base = blk * 1024;
        int v[4];
        int s = 0;
#pragma unroll
        for (int k = 0; k < 4; ++k) {
            int i = base + tx * 4 + k;
            v[k] = (i < SCANH_N) ? arr[i] : 0;
            s += v[k];
        }
        tmp[tx] = s;
        __syncthreads();
        for (int o = 1; o < 256; o <<= 1) {
            int t = (tx >= o) ? tmp[tx - o] : 0;
            __syncthreads();
            tmp[tx] += t;
            __syncthreads();
        }
        int excl = (tx == 0) ? 0 : tmp[tx - 1];
#pragma unroll
        for (int k = 0; k < 4; ++k) {
            int i = base + tx * 4 + k;
            if (i < SCANH_N) arr[i] = excl;
            excl += v[k];
        }
        if (tx == 255) bsum[blk] = tmp[255];
        return;
    }
    // ---- encoder
    const bool user = blockIdx.x < NBLK16;
    const int blk = user ? blockIdx.x : blockIdx.x - NBLK16;
    const int K = user ? 64 : 32;
    const int kshift = user ? 6 : 5;
    const int stride = K + 8;
    const float* x = user ? xu : xi;
    const ushortT* wT = user ? wTu : wTi;
    const float* bias = user ? bu : bi;
    ushortT* out = user ? outu : outi;
    const int rowbase = blk * 16;
    {
        int i = tx * 4;
        if (i < 16 * K) {
            const float4 v = *reinterpret_cast<const float4*>(&x[(size_t)rowbase * K + i]);
            int r = i >> kshift, c = i & (K - 1);
            uint2 w;
            w.x = pack2(v.x, v.y);
            w.y = pack2(v.z, v.w);
            *reinterpret_cast<uint2*>(&xs[r * stride + c]) = w;
        }
    }
    __syncthreads();
    const int wave = tx >> 6, lane = tx & 63;
    const int ln = lane & 15, quad = lane >> 4;
    const int n0 = wave * 32;
    floatx4 acc0 = {0.f, 0.f, 0.f, 0.f};
    floatx4 acc1 = {0.f, 0.f, 0.f, 0.f};
    for (int k0 = 0; k0 < K; k0 += 32) {
        short8 af = *reinterpret_cast<const short8*>(&xs[ln * stride + k0 + quad * 8]);
        short8 b0 = *reinterpret_cast<const short8*>(&wT[(n0 + ln) * K + k0 + quad * 8]);
        short8 b1 = *reinterpret_cast<const short8*>(&wT[(n0 + 16 + ln) * K + k0 + quad * 8]);
        acc0 = __builtin_amdgcn_mfma_f32_16x16x32_bf16(af, b0, acc0, 0, 0, 0);
        acc1 = __builtin_amdgcn_mfma_f32_16x16x32_bf16(af, b1, acc1, 0, 0, 0);
    }
    const float b0v = bias[n0 + ln], b1v = bias[n0 + 16 + ln];
#pragma unroll
    for (int r = 0; r < 4; ++r) {
        int row = rowbase + quad * 4 + r;
        out[(size_t)row * H + n0 + ln] = f2bf(fmaxf(acc0[r] + b0v, 0.f));
        out[(size_t)row * H + n0 + 16 + ln] = f2bf(fmaxf(acc1[r] + b1v, 0.f));
    }
}

// 256-thread LDS exclusive scan of NBS raw block sums into bpre[256].
// Callers must __syncthreads() after return before reading bpre.
static __device__ __forceinline__ void bsum_scan(const int* __restrict__ bsum, int* bpre, int tx) {
    int v = (tx < NBS) ? bsum[tx] : 0;
    bpre[tx] = v;
    __syncthreads();
    for (int o = 1; o < 256; o <<= 1) {
        int t = (tx >= o) ? bpre[tx - o] : 0;
        __syncthreads();
        bpre[tx] += t;
        __syncthreads();
    }
    int excl = (tx == 0) ? 0 : bpre[tx - 1];
    __syncthreads();
    bpre[tx] = excl;
}

// ---------------------------------------------------------------------------
// D3: scatter packed (dst<<16 | src) into per-(bucket,chunk) exclusive ranges
// ---------------------------------------------------------------------------
__global__ void scatterA_kernel(const int* __restrict__ e0, const int* __restrict__ e1,
                                const int* __restrict__ scanH0, const int* __restrict__ bsum0,
                                const int* __restrict__ scanH1, const int* __restrict__ bsum1,
                                uintT* __restrict__ stage0, uintT* __restrict__ stage1) {
    __shared__ int cur[NBUK];
    __shared__ int bpre[256];
    const int tx = threadIdx.x;
    const bool first = blockIdx.x < BCH;
    const int c = first ? blockIdx.x : blockIdx.x - BCH;
    const int* ei = first ? e0 : e1;
    const int* scanH = first ? scanH0 : scanH1;
    const int* bsum = first ? bsum0 : bsum1;
    uintT* stage = first ? stage0 : stage1;

    bsum_scan(bsum, bpre, tx);
    __syncthreads();
    for (int i = tx; i < NBUK; i += 256) {
        int idx = i * BCH + c;
        cur[i] = scanH[idx] + bpre[idx >> 10];
    }
    __syncthreads();
    const int base = c * CHUNK;
    for (int e = tx; e < CHUNK; e += 256) {
        int s = ei[base + e];
        int d = ei[NEDGE + base + e];
        int pos = atomicAdd(&cur[d >> 6], 1);
        stage[pos] = ((uintT)d << 16) | (uintT)s;
    }
}

// ---------------------------------------------------------------------------
// D4: per-bucket local sort by dst; dense u16 srcidx + off[]
// ---------------------------------------------------------------------------
__global__ void passB_kernel(const uintT* __restrict__ stage0, const int* __restrict__ scanH0,
                             const int* __restrict__ bsum0, ushortT* __restrict__ srcidx0,
                             int* __restrict__ off0,
                             const uintT* __restrict__ stage1, const int* __restrict__ scanH1,
                             const int* __restrict__ bsum1, ushortT* __restrict__ srcidx1,
                             int* __restrict__ off1) {
    __shared__ uintT inbuf[BCAP];
    __shared__ ushortT outbuf[BCAP];
    __shared__ int hist[64], scn[64], cur[64];
    __shared__ int bpre[256];
    const int tx = threadIdx.x;
    const bool first = blockIdx.x < NBUK;
    const int b = first ? blockIdx.x : blockIdx.x - NBUK;
    const uintT* stage = first ? stage0 : stage1;
    const int* scanH = first ? scanH0 : scanH1;
    const int* bsum = first ? bsum0 : bsum1;
    ushortT* srcidx = first ? srcidx0 : srcidx1;
    int* off = first ? off0 : off1;

    bsum_scan(bsum, bpre, tx);
    __syncthreads();
    if (tx < 64) hist[tx] = 0;

    const int ib = b * BCH;
    const int base = scanH[ib] + bpre[ib >> 10];
    const int end = (b == NBUK - 1) ? NEDGE : (scanH[ib + BCH] + bpre[(ib + BCH) >> 10]);
    const int size = end - base;

    for (int i = tx; i < size; i += 256) inbuf[i] = stage[base + i];
    __syncthreads();
    for (int i = tx; i < size; i += 256) atomicAdd(&hist[(inbuf[i] >> 16) & 63], 1);
    __syncthreads();
    if (tx == 0) {
        int s = 0;
#pragma unroll
        for (int i = 0; i < 64; ++i) { scn[i] = s; s += hist[i]; }
    }
    __syncthreads();
    if (tx < 64) cur[tx] = scn[tx];
    __syncthreads();
    for (int i = tx; i < size; i += 256) {
        uintT w = inbuf[i];
        int pos = atomicAdd(&cur[(w >> 16) & 63], 1);
        outbuf[pos] = (ushortT)(w & 0xffffu);
    }
    __syncthreads();
    for (int i = tx; i < size; i += 256) srcidx[base + i] = outbuf[i];
    if (tx < 64) {
        int d = b * 64 + tx;
        if (d < NNODE) off[d] = base + scn[tx];
    }
    if (b == NBUK - 1 && tx == 64) off[NNODE] = NEDGE;
}

// ---------------------------------------------------------------------------
// D5/D7: dedicated gather-mean, wide-load edition. One WAVE per dst row.
// 16-lane group g covers one 256B source row via dwordx4; one wave-load
// fetches 4 edges. Main loop = unmasked 16-edge chunks (packed f32 adds);
// tail = unmasked 4-edge chunks + one masked 4-edge chunk (cuts the 1.46x
// edge-overrun + mask VALU that bound r9).
// ---------------------------------------------------------------------------
__global__ void gather2_kernel(const ushortT* __restrict__ xsrcA, const ushortT* __restrict__ srcA,
                               const int* __restrict__ offA, ushortT* __restrict__ aggA,
                               const ushortT* __restrict__ xsrcB, const ushortT* __restrict__ srcB,
                               const int* __restrict__ offB, ushortT* __restrict__ aggB) {
    const bool first = blockIdx.x < GBLK;
    const int blk = first ? blockIdx.x : blockIdx.x - GBLK;
    const ushortT* xsrc = first ? xsrcA : xsrcB;
    const ushortT* srcidx = first ? srcA : srcB;
    const int* off = first ? offA : offB;
    ushortT* agg = first ? aggA : aggB;

    const int wave = threadIdx.x >> 6, lane = threadIdx.x & 63;
    const int g = lane >> 4, gl = lane & 15;
    const int row = blk * 4 + wave;
    const int start = off[row];
    const int deg = off[row + 1] - start;
    const ushortT* sidx = srcidx + start;
    const uint4* srcv = (const uint4*)xsrc;   // row = 16 x uint4

    float2v acc0 = {0.f, 0.f}, acc1 = {0.f, 0.f}, acc2 = {0.f, 0.f}, acc3 = {0.f, 0.f};
    int j = 0;
    for (; j + 16 <= deg; j += 16) {          // unmasked, 4 loads in flight
        uint4 v[4];
#pragma unroll
        for (int u = 0; u < 4; ++u) {
            int s = sidx[j + u * 4 + g];
            v[u] = srcv[(size_t)s * 16 + gl];
        }
#pragma unroll
        for (int u = 0; u < 4; ++u) {
            acc0 += up2(v[u].x);
            acc1 += up2(v[u].y);
            acc2 += up2(v[u].z);
            acc3 += up2(v[u].w);
        }
    }
    for (; j + 4 <= deg; j += 4) {            // unmasked 4-edge chunks
        int s = sidx[j + g];
        uint4 v = srcv[(size_t)s * 16 + gl];
        acc0 += up2(v.x);
        acc1 += up2(v.y);
        acc2 += up2(v.z);
        acc3 += up2(v.w);
    }
    if (j < deg) {                            // one masked 4-edge chunk
        int e = j + g;
        int ec = (e < deg) ? e : deg - 1;
        int s = sidx[ec];
        uint4 v = srcv[(size_t)s * 16 + gl];
        float m = (e < deg) ? 1.f : 0.f;
        acc0.x = fmaf(lo2f(v.x), m, acc0.x); acc0.y = fmaf(hi2f(v.x), m, acc0.y);
        acc1.x = fmaf(lo2f(v.y), m, acc1.x); acc1.y = fmaf(hi2f(v.y), m, acc1.y);
        acc2.x = fmaf(lo2f(v.z), m, acc2.x); acc2.y = fmaf(hi2f(v.z), m, acc2.y);
        acc3.x = fmaf(lo2f(v.w), m, acc3.x); acc3.y = fmaf(hi2f(v.w), m, acc3.y);
    }
#pragma unroll
    for (int o = 16; o <= 32; o <<= 1) {
        acc0.x += __shfl_xor(acc0.x, o, 64); acc0.y += __shfl_xor(acc0.y, o, 64);
        acc1.x += __shfl_xor(acc1.x, o, 64); acc1.y += __shfl_xor(acc1.y, o, 64);
        acc2.x += __shfl_xor(acc2.x, o, 64); acc2.y += __shfl_xor(acc2.y, o, 64);
        acc3.x += __shfl_xor(acc3.x, o, 64); acc3.y += __shfl_xor(acc3.y, o, 64);
    }
    if (lane < 16) {
        const float inv = 1.f / fmaxf((float)deg, 1.f);
        uint4 o;
        o.x = pack2(acc0.x * inv, acc0.y * inv);
        o.y = pack2(acc1.x * inv, acc1.y * inv);
        o.z = pack2(acc2.x * inv, acc2.y * inv);
        o.w = pack2(acc3.x * inv, acc3.y * inv);
        ((uint4*)agg)[(size_t)row * 16 + gl] = o;
    }
}

// ---------------------------------------------------------------------------
// D6/D8: streaming SAGE MFMA, 64 rows/block, B fragments in registers.
//   out = relu( l2norm( [agg | xdst] @ [wl;wr] + bl ) ) + xdst
// ---------------------------------------------------------------------------
__global__ void sageM_kernel(
    const ushortT* __restrict__ aggA, const ushortT* __restrict__ xdstA,
    const ushortT* __restrict__ wlTA, const float* __restrict__ blA,
    const ushortT* __restrict__ wrTA, ushortT* __restrict__ outA,
    const ushortT* __restrict__ aggB, const ushortT* __restrict__ xdstB,
    const ushortT* __restrict__ wlTB, const float* __restrict__ blB,
    const ushortT* __restrict__ wrTB, ushortT* __restrict__ outB) {
    __shared__ ushortT At[64 * 264];     // 33.8 KB: [row][0:128)=agg, [128:256)=xdst
    __shared__ float part[4][64];
    __shared__ float scl[64];
    const bool first = blockIdx.x < SAGEB;
    const int blk = first ? blockIdx.x : blockIdx.x - SAGEB;
    const ushortT* agg  = first ? aggA  : aggB;
    const ushortT* xdst = first ? xdstA : xdstB;
    const ushortT* wlT  = first ? wlTA  : wlTB;
    const float* bl     = first ? blA   : blB;
    const ushortT* wrT  = first ? wrTA  : wrTB;
    ushortT* out        = first ? outA  : outB;

    const int tx = threadIdx.x;
    const int rowbase = blk * 64;
    const int wave = tx >> 6, lane = tx & 63;
    const int ln = lane & 15, quad = lane >> 4;
    const int n0 = wave * 32;

#pragma unroll
    for (int it = 0; it < 4; ++it) {
        int i = it * 256 + tx;           // 0..1023
        int r = i >> 4, ch = i & 15;
        int row = rowbase + r;
        size_t rs = (size_t)((row < NNODE) ? row : NNODE - 1) * H + ch * 8;
        *reinterpret_cast<short8*>(&At[r * 264 + ch * 8]) =
            *reinterpret_cast<const short8*>(&agg[rs]);
        *reinterpret_cast<short8*>(&At[r * 264 + 128 + ch * 8]) =
            *reinterpret_cast<const short8*>(&xdst[rs]);
    }

    short8 bf[8][2];
#pragma unroll
    for (int kt = 0; kt < 8; ++kt) {
        const ushortT* wT = (kt < 4) ? wlT : wrT;
        const int kk = (kt & 3) * 32 + quad * 8;
        bf[kt][0] = *reinterpret_cast<const short8*>(&wT[(n0 + ln) * 128 + kk]);
        bf[kt][1] = *reinterpret_cast<const short8*>(&wT[(n0 + 16 + ln) * 128 + kk]);
    }
    __syncthreads();

    floatx4 acc[4][2] = {};
#pragma unroll
    for (int ms = 0; ms < 4; ++ms) {
#pragma unroll
        for (int kt = 0; kt < 8; ++kt) {
            short8 af = *reinterpret_cast<const short8*>(
                &At[(ms * 16 + ln) * 264 + kt * 32 + quad * 8]);
            acc[ms][0] = __builtin_amdgcn_mfma_f32_16x16x32_bf16(af, bf[kt][0], acc[ms][0], 0, 0, 0);
            acc[ms][1] = __builtin_amdgcn_mfma_f32_16x16x32_bf16(af, bf[kt][1], acc[ms][1], 0, 0, 0);
        }
    }

    const float bl0 = bl[n0 + ln];
    const float bl1 = bl[n0 + 16 + ln];
#pragma unroll
    for (int ms = 0; ms < 4; ++ms) {
#pragma unroll
        for (int r = 0; r < 4; ++r) {
            float v0 = acc[ms][0][r] + bl0;
            float v1 = acc[ms][1][r] + bl1;
            acc[ms][0][r] = v0;
            acc[ms][1][r] = v1;
            float s = v0 * v0 + v1 * v1;
            s += __shfl_xor(s, 1, 64);
            s += __shfl_xor(s, 2, 64);
            s += __shfl_xor(s, 4, 64);
            s += __shfl_xor(s, 8, 64);
            if (ln == 0) part[wave][ms * 16 + quad * 4 + r] = s;
        }
    }
    __syncthreads();
    if (tx < 64) {
        float t = part[0][tx] + part[1][tx] + part[2][tx] + part[3][tx];
        scl[tx] = 1.f / fmaxf(sqrtf(t), 1e-12f);
    }
    __syncthreads();
#pragma unroll
    for (int ms = 0; ms < 4; ++ms) {
#pragma unroll
        for (int r = 0; r < 4; ++r) {
            const int lr = ms * 16 + quad * 4 + r;
            const int row = rowbase + lr;
            if (row < NNODE) {
                const float sc = scl[lr];
                float o0 = fmaxf(acc[ms][0][r] * sc, 0.f) + bf2f(At[lr * 264 + 128 + n0 + ln]);
                float o1 = fmaxf(acc[ms][1][r] * sc, 0.f) + bf2f(At[lr * 264 + 128 + n0 + 16 + ln]);
                out[(size_t)row * H + n0 + ln] = f2bf(o0);
                out[(size_t)row * H + n0 + 16 + ln] = f2bf(o1);
            }
        }
    }
}

// ---------------------------------------------------------------------------
// D9: head, 64 rows/block (w1 fragments in registers)
// ---------------------------------------------------------------------------
__global__ void head_kernel(const ushortT* __restrict__ hu, const ushortT* __restrict__ w1T,
                            const float* __restrict__ b1, const float* __restrict__ w2,
                            const float* __restrict__ b2, float* __restrict__ out) {
    __shared__ ushortT hs[64 * 136];
    __shared__ float zs[64 * 72];
    const int tx = threadIdx.x;
    const int rowbase = blockIdx.x * 64;
    const int wave = tx >> 6, lane = tx & 63;
    const int ln = lane & 15, quad = lane >> 4;
#pragma unroll
    for (int it = 0; it < 4; ++it) {
        int i = it * 256 + tx;
        int r = i >> 4, ch = i & 15;
        int row = rowbase + r;
        size_t rs = (size_t)((row < NNODE) ? row : NNODE - 1) * H + ch * 8;
        *reinterpret_cast<short8*>(&hs[r * 136 + ch * 8]) =
            *reinterpret_cast<const short8*>(&hu[rs]);
    }
    short8 bf[4];
#pragma unroll
    for (int kt = 0; kt < 4; ++kt)
        bf[kt] = *reinterpret_cast<const short8*>(&w1T[(wave * 16 + ln) * 128 + kt * 32 + quad * 8]);
    __syncthreads();
    floatx4 acc[4] = {};
#pragma unroll
    for (int ms = 0; ms < 4; ++ms) {
#pragma unroll
        for (int kt = 0; kt < 4; ++kt) {
            short8 af = *reinterpret_cast<const short8*>(
                &hs[(ms * 16 + ln) * 136 + kt * 32 + quad * 8]);
            acc[ms] = __builtin_amdgcn_mfma_f32_16x16x32_bf16(af, bf[kt], acc[ms], 0, 0, 0);
        }
    }
    const float bv = b1[wave * 16 + ln];
#pragma unroll
    for (int ms = 0; ms < 4; ++ms)
#pragma unroll
        for (int r = 0; r < 4; ++r)
            zs[(ms * 16 + quad * 4 + r) * 72 + wave * 16 + ln] = fmaxf(acc[ms][r] + bv, 0.f);
    __syncthreads();
#pragma unroll
    for (int u = 0; u < 2; ++u) {
        int i = tx * 2 + u;
        int r = i >> 3, c = i & 7;
        int row = rowbase + r;
        if (row < NNODE) {
            float a = b2[c];
#pragma unroll 8
            for (int k = 0; k < 64; ++k) a += zs[r * 72 + k] * w2[k * 8 + c];
            out[(size_t)row * 8 + c] = a;
        }
    }
}

// ---------------------------------------------------------------------------
extern "C" void kernel_launch(void* const* d_in, const int* in_sizes, int n_in,
                              void* d_out, int out_size, void* d_ws, size_t ws_size,
                              hipStream_t stream) {
    const float* x_user     = (const float*)d_in[0];
    const float* x_item     = (const float*)d_in[1];
    const int*   ei_u2i     = (const int*)d_in[2];
    const int*   ei_i2u     = (const int*)d_in[3];
    const float* enc_user_w = (const float*)d_in[4];
    const float* enc_user_b = (const float*)d_in[5];
    const float* enc_item_w = (const float*)d_in[6];
    const float* enc_item_b = (const float*)d_in[7];
    const float* W[12];
    for (int i = 0; i < 12; ++i) W[i] = (const float*)d_in[8 + i];
    const float* head_w1 = (const float*)d_in[20];
    const float* head_b1 = (const float*)d_in[21];
    const float* head_w2 = (const float*)d_in[22];
    const float* head_b2 = (const float*)d_in[23];
    float* out = (float*)d_out;

    const size_t S = (size_t)NNODE * H;
    ushortT* huA  = (ushortT*)d_ws;
    ushortT* huB  = huA + S;
    ushortT* hiA  = huB + S;
    ushortT* hiB  = hiA + S;
    ushortT* wT   = hiB + S;                  // 151552 bf16
    int*    scanH_i = (int*)(wT + 151552);    // [SCANH_N]
    int*    scanH_u = scanH_i + SCANH_N;
    int*    bsum_i  = scanH_u + SCANH_N;      // [256] raw block sums
    int*    bsum_u  = bsum_i + 256;
    int*    off_i   = bsum_u + 256;           // [NNODE+1]
    int*    off_u   = off_i + NNODE + 1;
    uintT*  stage_i = (uintT*)(off_u + NNODE + 1);  // [NEDGE]
    uintT*  stage_u = stage_i + NEDGE;
    ushortT* src_i  = (ushortT*)(stage_u + NEDGE);  // [NEDGE] u16
    ushortT* src_u  = src_i + NEDGE;
    ushortT* aggI   = src_u + NEDGE;          // [S]
    ushortT* aggU   = aggI + S;               // [S]

    const ushortT* wTeu = wT + 131072;
    const ushortT* wTei = wT + 139264;
    const ushortT* w1T  = wT + 143360;

    // D1: weight converts + edge histograms
    setup_kernel<<<592 + 2 * BCH, 256, 0, stream>>>(
        W[0], W[2], W[3], W[5], W[6], W[8], W[9], W[11],
        enc_user_w, enc_item_w, head_w1, wT,
        ei_u2i, ei_i2u, scanH_i, scanH_u);

    // D2: encoders + scanH scans
    encscan_kernel<<<2 * NBLK16 + 2 * NBS, 256, 0, stream>>>(
        x_user, wTeu, enc_user_b, x_item, wTei, enc_item_b, huA, hiA,
        scanH_i, bsum_i, scanH_u, bsum_u);

    // D3/D4: locality-preserving scatter, then per-bucket sort -> CSR
    scatterA_kernel<<<2 * BCH, 256, 0, stream>>>(ei_u2i, ei_i2u, scanH_i, bsum_i,
                                                 scanH_u, bsum_u, stage_i, stage_u);
    passB_kernel<<<2 * NBUK, 256, 0, stream>>>(stage_i, scanH_i, bsum_i, src_i, off_i,
                                               stage_u, scanH_u, bsum_u, src_u, off_u);

    // layer 0
    gather2_kernel<<<2 * GBLK, 256, 0, stream>>>(huA, src_i, off_i, aggI,
                                                 hiA, src_u, off_u, aggU);
    sageM_kernel<<<2 * SAGEB, 256, 0, stream>>>(
        aggI, hiA, wT + 0 * 16384, W[1], wT + 1 * 16384, hiB,
        aggU, huA, wT + 2 * 16384, W[4], wT + 3 * 16384, huB);

    // layer 1
    gather2_kernel<<<2 * GBLK, 256, 0, stream>>>(huB, src_i, off_i, aggI,
                                                 hiB, src_u, off_u, aggU);
    sageM_kernel<<<2 * SAGEB, 256, 0, stream>>>(
        aggI, hiB, wT + 4 * 16384, W[7], wT + 5 * 16384, hiA,
        aggU, huB, wT + 6 * 16384, W[10], wT + 7 * 16384, huA);

    head_kernel<<<SAGEB, 256, 0, stream>>>(huA, w1T, head_b1, head_w2, head_b2, out);
}

// Round 11
// 334.946 us; speedup vs baseline: 1.0303x; 1.0303x over previous
//
#include <hip/hip_runtime.h>
#include <math.h>

#define H 128
#define NNODE 50000
#define NEDGE 800000
#define NBLK16 3125      // NNODE / 16
#define NBUK 782         // buckets of 64 dst nodes: ceil(50000/64)
#define BCH 256          // edge chunks per type
#define CHUNK 3125       // NEDGE / BCH
#define SCANH_N 200192   // NBUK * BCH
#define NBS 196          // scan blocks per array (1024 elems each)
#define BCAP 1536        // max edges per bucket (mean 1024)
#define GBLK 12500       // gather blocks per direction (4 rows/block, 1 row/wave)
#define SAGEB 782        // sage blocks per direction (64 rows/block)

typedef unsigned short ushortT;
typedef unsigned int uintT;
typedef __attribute__((ext_vector_type(8))) short short8;
typedef __attribute__((ext_vector_type(4))) float floatx4;
typedef __attribute__((ext_vector_type(2))) float float2v;

static __device__ __forceinline__ float bf2f(ushortT u) {
    union { uintT i; float f; } c; c.i = ((uintT)u) << 16; return c.f;
}
static __device__ __forceinline__ ushortT f2bf(float f) {
    union { float f; uintT i; } c; c.f = f;
    uintT lsb = (c.i >> 16) & 1;
    c.i += 0x7fffu + lsb;          // round-to-nearest-even
    return (ushortT)(c.i >> 16);
}
static __device__ __forceinline__ float lo2f(uintT v) {
    union { uintT i; float f; } c; c.i = v << 16; return c.f;
}
static __device__ __forceinline__ float hi2f(uintT v) {
    union { uintT i; float f; } c; c.i = v & 0xffff0000u; return c.f;
}
static __device__ __forceinline__ uintT pack2(float a, float b) {
    return (uintT)f2bf(a) | ((uintT)f2bf(b) << 16);
}
static __device__ __forceinline__ float2v up2(uintT v) {
    return (float2v){lo2f(v), hi2f(v)};
}

// ---------------------------------------------------------------------------
// D1: weight convert+transpose (blocks 0..591) + edge histograms (592..1103)
// ---------------------------------------------------------------------------
__global__ void setup_kernel(const float* __restrict__ s0, const float* __restrict__ s1,
                             const float* __restrict__ s2, const float* __restrict__ s3,
                             const float* __restrict__ s4, const float* __restrict__ s5,
                             const float* __restrict__ s6, const float* __restrict__ s7,
                             const float* __restrict__ seu, const float* __restrict__ sei,
                             const float* __restrict__ sw1, ushortT* __restrict__ wT,
                             const int* __restrict__ e0, const int* __restrict__ e1,
                             int* __restrict__ scanH0, int* __restrict__ scanH1) {
    __shared__ int hist[NBUK];
    const int b = blockIdx.x, t = threadIdx.x;
    if (b < 512) {
        const int m = b >> 6;
        const float* s = (m == 0) ? s0 : (m == 1) ? s1 : (m == 2) ? s2 : (m == 3) ? s3
                       : (m == 4) ? s4 : (m == 5) ? s5 : (m == 6) ? s6 : s7;
        int i = (b & 63) * 256 + t;
        int k = i >> 7, c = i & 127;
        wT[m * 16384 + c * 128 + k] = f2bf(s[k * 128 + c]);
    } else if (b < 544) {
        int i = (b - 512) * 256 + t;
        int k = i >> 7, c = i & 127;
        wT[131072 + c * 64 + k] = f2bf(seu[k * 128 + c]);
    } else if (b < 560) {
        int i = (b - 544) * 256 + t;
        int k = i >> 7, c = i & 127;
        wT[139264 + c * 32 + k] = f2bf(sei[k * 128 + c]);
    } else if (b < 592) {
        int i = (b - 560) * 256 + t;
        int k = i >> 6, c = i & 63;
        wT[143360 + c * 128 + k] = f2bf(sw1[k * 64 + c]);
    } else {
        const int hb = b - 592;
        const bool first = hb < BCH;
        const int c = first ? hb : hb - BCH;
        const int* edst = (first ? e0 : e1) + NEDGE + c * CHUNK;
        int* scanH = first ? scanH0 : scanH1;
        for (int i = t; i < NBUK; i += 256) hist[i] = 0;
        __syncthreads();
        for (int e = t; e < CHUNK; e += 256) atomicAdd(&hist[edst[e] >> 6], 1);
        __syncthreads();
        for (int i = t; i < NBUK; i += 256) scanH[i * BCH + c] = hist[i];
    }
}

// ---------------------------------------------------------------------------
// D2: merged encoders (MFMA, blocks [0,6250)) + scanH exclusive scans (rest)
// ---------------------------------------------------------------------------
__global__ void encscan_kernel(const float* __restrict__ xu, const ushortT* __restrict__ wTu,
                               const float* __restrict__ bu,
                               const float* __restrict__ xi, const ushortT* __restrict__ wTi,
                               const float* __restrict__ bi,
                               ushortT* __restrict__ outu, ushortT* __restrict__ outi,
                               int* __restrict__ scanH0, int* __restrict__ bsum0,
                               int* __restrict__ scanH1, int* __restrict__ bsum1) {
    __shared__ ushortT xs[16 * 72];
    __shared__ int tmp[256];
    const int tx = threadIdx.x;
    if (blockIdx.x >= 2 * NBLK16) {
        const int sb = blockIdx.x - 2 * NBLK16;
        const bool first = sb < NBS;
        const int blk = first ? sb : sb - NBS;
        int* arr = first ? scanH0 : scanH1;
        int* bsum = first ? bsum0 : bsum1;
        const int base = blk * 1024;
        int v[4];
        int s = 0;
#pragma unroll
        for (int k = 0; k < 4; ++k) {
            int i = base + tx * 4 + k;
            v[k] = (i < SCANH_N) ? arr[i] : 0;
            s += v[k];
        }
        tmp[tx] = s;
        __syncthreads();
        for (int o = 1; o < 256; o <<= 1) {
            int t = (tx >= o) ? tmp[tx - o] : 0;
            __syncthreads();
            tmp[tx] += t;
            __syncthreads();
        }
        int excl = (tx == 0) ? 0 : tmp[tx - 1];
#pragma unroll
        for (int k = 0; k < 4; ++k) {
            int i = base + tx * 4 + k;
            if (i < SCANH_N) arr[i] = excl;
            excl += v[k];
        }
        if (tx == 255) bsum[blk] = tmp[255];
        return;
    }
    const bool user = blockIdx.x < NBLK16;
    const int blk = user ? blockIdx.x : blockIdx.x - NBLK16;
    const int K = user ? 64 : 32;
    const int kshift = user ? 6 : 5;
    const int stride = K + 8;
    const float* x = user ? xu : xi;
    const ushortT* wT = user ? wTu : wTi;
    const float* bias = user ? bu : bi;
    ushortT* out = user ? outu : outi;
    const int rowbase = blk * 16;
    {
        int i = tx * 4;
        if (i < 16 * K) {
            const float4 v = *reinterpret_cast<const float4*>(&x[(size_t)rowbase * K + i]);
            int r = i >> kshift, c = i & (K - 1);
            uint2 w;
            w.x = pack2(v.x, v.y);
            w.y = pack2(v.z, v.w);
            *reinterpret_cast<uint2*>(&xs[r * stride + c]) = w;
        }
    }
    __syncthreads();
    const int wave = tx >> 6, lane = tx & 63;
    const int ln = lane & 15, quad = lane >> 4;
    const int n0 = wave * 32;
    floatx4 acc0 = {0.f, 0.f, 0.f, 0.f};
    floatx4 acc1 = {0.f, 0.f, 0.f, 0.f};
    for (int k0 = 0; k0 < K; k0 += 32) {
        short8 af = *reinterpret_cast<const short8*>(&xs[ln * stride + k0 + quad * 8]);
        short8 b0 = *reinterpret_cast<const short8*>(&wT[(n0 + ln) * K + k0 + quad * 8]);
        short8 b1 = *reinterpret_cast<const short8*>(&wT[(n0 + 16 + ln) * K + k0 + quad * 8]);
        acc0 = __builtin_amdgcn_mfma_f32_16x16x32_bf16(af, b0, acc0, 0, 0, 0);
        acc1 = __builtin_amdgcn_mfma_f32_16x16x32_bf16(af, b1, acc1, 0, 0, 0);
    }
    const float b0v = bias[n0 + ln], b1v = bias[n0 + 16 + ln];
#pragma unroll
    for (int r = 0; r < 4; ++r) {
        int row = rowbase + quad * 4 + r;
        out[(size_t)row * H + n0 + ln] = f2bf(fmaxf(acc0[r] + b0v, 0.f));
        out[(size_t)row * H + n0 + 16 + ln] = f2bf(fmaxf(acc1[r] + b1v, 0.f));
    }
}

// 256-thread LDS exclusive scan of NBS raw block sums into bpre[256].
static __device__ __forceinline__ void bsum_scan(const int* __restrict__ bsum, int* bpre, int tx) {
    int v = (tx < NBS) ? bsum[tx] : 0;
    bpre[tx] = v;
    __syncthreads();
    for (int o = 1; o < 256; o <<= 1) {
        int t = (tx >= o) ? bpre[tx - o] : 0;
        __syncthreads();
        bpre[tx] += t;
        __syncthreads();
    }
    int excl = (tx == 0) ? 0 : bpre[tx - 1];
    __syncthreads();
    bpre[tx] = excl;
}

// ---------------------------------------------------------------------------
// D3: scatter packed (dst<<16 | src) into per-(bucket,chunk) exclusive ranges
// ---------------------------------------------------------------------------
__global__ void scatterA_kernel(const int* __restrict__ e0, const int* __restrict__ e1,
                                const int* __restrict__ scanH0, const int* __restrict__ bsum0,
                                const int* __restrict__ scanH1, const int* __restrict__ bsum1,
                                uintT* __restrict__ stage0, uintT* __restrict__ stage1) {
    __shared__ int cur[NBUK];
    __shared__ int bpre[256];
    const int tx = threadIdx.x;
    const bool first = blockIdx.x < BCH;
    const int c = first ? blockIdx.x : blockIdx.x - BCH;
    const int* ei = first ? e0 : e1;
    const int* scanH = first ? scanH0 : scanH1;
    const int* bsum = first ? bsum0 : bsum1;
    uintT* stage = first ? stage0 : stage1;

    bsum_scan(bsum, bpre, tx);
    __syncthreads();
    for (int i = tx; i < NBUK; i += 256) {
        int idx = i * BCH + c;
        cur[i] = scanH[idx] + bpre[idx >> 10];
    }
    __syncthreads();
    const int base = c * CHUNK;
    for (int e = tx; e < CHUNK; e += 256) {
        int s = ei[base + e];
        int d = ei[NEDGE + base + e];
        int pos = atomicAdd(&cur[d >> 6], 1);
        stage[pos] = ((uintT)d << 16) | (uintT)s;
    }
}

// ---------------------------------------------------------------------------
// D4: per-bucket local sort by dst; dense u16 srcidx + off[]
// ---------------------------------------------------------------------------
__global__ void passB_kernel(const uintT* __restrict__ stage0, const int* __restrict__ scanH0,
                             const int* __restrict__ bsum0, ushortT* __restrict__ srcidx0,
                             int* __restrict__ off0,
                             const uintT* __restrict__ stage1, const int* __restrict__ scanH1,
                             const int* __restrict__ bsum1, ushortT* __restrict__ srcidx1,
                             int* __restrict__ off1) {
    __shared__ uintT inbuf[BCAP];
    __shared__ ushortT outbuf[BCAP];
    __shared__ int hist[64], scn[64], cur[64];
    __shared__ int bpre[256];
    const int tx = threadIdx.x;
    const bool first = blockIdx.x < NBUK;
    const int b = first ? blockIdx.x : blockIdx.x - NBUK;
    const uintT* stage = first ? stage0 : stage1;
    const int* scanH = first ? scanH0 : scanH1;
    const int* bsum = first ? bsum0 : bsum1;
    ushortT* srcidx = first ? srcidx0 : srcidx1;
    int* off = first ? off0 : off1;

    bsum_scan(bsum, bpre, tx);
    __syncthreads();
    if (tx < 64) hist[tx] = 0;

    const int ib = b * BCH;
    const int base = scanH[ib] + bpre[ib >> 10];
    const int end = (b == NBUK - 1) ? NEDGE : (scanH[ib + BCH] + bpre[(ib + BCH) >> 10]);
    const int size = end - base;

    for (int i = tx; i < size; i += 256) inbuf[i] = stage[base + i];
    __syncthreads();
    for (int i = tx; i < size; i += 256) atomicAdd(&hist[(inbuf[i] >> 16) & 63], 1);
    __syncthreads();
    if (tx == 0) {
        int s = 0;
#pragma unroll
        for (int i = 0; i < 64; ++i) { scn[i] = s; s += hist[i]; }
    }
    __syncthreads();
    if (tx < 64) cur[tx] = scn[tx];
    __syncthreads();
    for (int i = tx; i < size; i += 256) {
        uintT w = inbuf[i];
        int pos = atomicAdd(&cur[(w >> 16) & 63], 1);
        outbuf[pos] = (ushortT)(w & 0xffffu);
    }
    __syncthreads();
    for (int i = tx; i < size; i += 256) srcidx[base + i] = outbuf[i];
    if (tx < 64) {
        int d = b * 64 + tx;
        if (d < NNODE) off[d] = base + scn[tx];
    }
    if (b == NBUK - 1 && tx == 64) off[NNODE] = NEDGE;
}

// ---------------------------------------------------------------------------
// D5/D7: dedicated gather-mean. One WAVE per dst row; 16-lane group g covers
// one 256B source row via dwordx4 (4 edges per wave-load).
// KEY (r11): the row's first 64 indices are loaded ONCE (coalesced per-lane),
// per-chunk indices come from __shfl (ds_bpermute) -> the idx-load memory hop
// is gone; each chunk is one memory hop with 4 row-loads in flight. Main loop
// unmasked + packed adds; tail = ONE masked 16-chunk (still 4 loads in
// flight, fixing r10's serial tail). deg>64 fallback is cold.
// ---------------------------------------------------------------------------
__global__ void gather2_kernel(const ushortT* __restrict__ xsrcA, const ushortT* __restrict__ srcA,
                               const int* __restrict__ offA, ushortT* __restrict__ aggA,
                               const ushortT* __restrict__ xsrcB, const ushortT* __restrict__ srcB,
                               const int* __restrict__ offB, ushortT* __restrict__ aggB) {
    const bool first = blockIdx.x < GBLK;
    const int blk = first ? blockIdx.x : blockIdx.x - GBLK;
    const ushortT* xsrc = first ? xsrcA : xsrcB;
    const ushortT* srcidx = first ? srcA : srcB;
    const int* off = first ? offA : offB;
    ushortT* agg = first ? aggA : aggB;

    const int wave = threadIdx.x >> 6, lane = threadIdx.x & 63;
    const int g = lane >> 4, gl = lane & 15;
    const int row = blk * 4 + wave;
    const int start = off[row];
    const int deg = off[row + 1] - start;
    const ushortT* sidx = srcidx + start;
    const uint4* srcv = (const uint4*)xsrc;   // row = 16 x uint4

    // one coalesced load of up to 64 indices into registers
    const int clampi = (deg > 0) ? deg - 1 : 0;
    const int myidx = sidx[(lane < clampi) ? lane : clampi];
    const int degc = (deg < 64) ? deg : 64;

    float2v acc0 = {0.f, 0.f}, acc1 = {0.f, 0.f}, acc2 = {0.f, 0.f}, acc3 = {0.f, 0.f};
    int j = 0;
    for (; j + 16 <= degc; j += 16) {         // unmasked, idx via shuffle
        uint4 v[4];
#pragma unroll
        for (int u = 0; u < 4; ++u) {
            int s = __shfl(myidx, j + u * 4 + g, 64);
            v[u] = srcv[(size_t)s * 16 + gl];
        }
#pragma unroll
        for (int u = 0; u < 4; ++u) {
            acc0 += up2(v[u].x);
            acc1 += up2(v[u].y);
            acc2 += up2(v[u].z);
            acc3 += up2(v[u].w);
        }
    }
    if (j < degc) {                           // one masked 16-chunk, 4 loads in flight
        uint4 v[4];
        float m[4];
#pragma unroll
        for (int u = 0; u < 4; ++u) {
            int e = j + u * 4 + g;
            int ee = (e < degc) ? e : degc - 1;   // e <= 63 here, safe shfl lane
            int s = __shfl(myidx, ee, 64);
            v[u] = srcv[(size_t)s * 16 + gl];
            m[u] = (e < degc) ? 1.f : 0.f;
        }
#pragma unroll
        for (int u = 0; u < 4; ++u) {
            acc0.x = fmaf(lo2f(v[u].x), m[u], acc0.x); acc0.y = fmaf(hi2f(v[u].x), m[u], acc0.y);
            acc1.x = fmaf(lo2f(v[u].y), m[u], acc1.x); acc1.y = fmaf(hi2f(v[u].y), m[u], acc1.y);
            acc2.x = fmaf(lo2f(v[u].z), m[u], acc2.x); acc2.y = fmaf(hi2f(v[u].z), m[u], acc2.y);
            acc3.x = fmaf(lo2f(v[u].w), m[u], acc3.x); acc3.y = fmaf(hi2f(v[u].w), m[u], acc3.y);
        }
    }
    if (deg > 64) {                           // cold path: P(deg>64) ~ 0
        for (int e0 = 64; e0 < deg; e0 += 4) {
            int e = e0 + g;
            int ec = (e < deg) ? e : deg - 1;
            int s = sidx[ec];
            uint4 v = srcv[(size_t)s * 16 + gl];
            float m = (e < deg) ? 1.f : 0.f;
            acc0.x = fmaf(lo2f(v.x), m, acc0.x); acc0.y = fmaf(hi2f(v.x), m, acc0.y);
            acc1.x = fmaf(lo2f(v.y), m, acc1.x); acc1.y = fmaf(hi2f(v.y), m, acc1.y);
            acc2.x = fmaf(lo2f(v.z), m, acc2.x); acc2.y = fmaf(hi2f(v.z), m, acc2.y);
            acc3.x = fmaf(lo2f(v.w), m, acc3.x); acc3.y = fmaf(hi2f(v.w), m, acc3.y);
        }
    }
#pragma unroll
    for (int o = 16; o <= 32; o <<= 1) {
        acc0.x += __shfl_xor(acc0.x, o, 64); acc0.y += __shfl_xor(acc0.y, o, 64);
        acc1.x += __shfl_xor(acc1.x, o, 64); acc1.y += __shfl_xor(acc1.y, o, 64);
        acc2.x += __shfl_xor(acc2.x, o, 64); acc2.y += __shfl_xor(acc2.y, o, 64);
        acc3.x += __shfl_xor(acc3.x, o, 64); acc3.y += __shfl_xor(acc3.y, o, 64);
    }
    if (lane < 16) {
        const float inv = 1.f / fmaxf((float)deg, 1.f);
        uint4 o;
        o.x = pack2(acc0.x * inv, acc0.y * inv);
        o.y = pack2(acc1.x * inv, acc1.y * inv);
        o.z = pack2(acc2.x * inv, acc2.y * inv);
        o.w = pack2(acc3.x * inv, acc3.y * inv);
        ((uint4*)agg)[(size_t)row * 16 + gl] = o;
    }
}

// ---------------------------------------------------------------------------
// D6/D8: streaming SAGE MFMA, 64 rows/block, B fragments in registers.
//   out = relu( l2norm( [agg | xdst] @ [wl;wr] + bl ) ) + xdst
// ---------------------------------------------------------------------------
__global__ void sageM_kernel(
    const ushortT* __restrict__ aggA, const ushortT* __restrict__ xdstA,
    const ushortT* __restrict__ wlTA, const float* __restrict__ blA,
    const ushortT* __restrict__ wrTA, ushortT* __restrict__ outA,
    const ushortT* __restrict__ aggB, const ushortT* __restrict__ xdstB,
    const ushortT* __restrict__ wlTB, const float* __restrict__ blB,
    const ushortT* __restrict__ wrTB, ushortT* __restrict__ outB) {
    __shared__ ushortT At[64 * 264];     // 33.8 KB
    __shared__ float part[4][64];
    __shared__ float scl[64];
    const bool first = blockIdx.x < SAGEB;
    const int blk = first ? blockIdx.x : blockIdx.x - SAGEB;
    const ushortT* agg  = first ? aggA  : aggB;
    const ushortT* xdst = first ? xdstA : xdstB;
    const ushortT* wlT  = first ? wlTA  : wlTB;
    const float* bl     = first ? blA   : blB;
    const ushortT* wrT  = first ? wrTA  : wrTB;
    ushortT* out        = first ? outA  : outB;

    const int tx = threadIdx.x;
    const int rowbase = blk * 64;
    const int wave = tx >> 6, lane = tx & 63;
    const int ln = lane & 15, quad = lane >> 4;
    const int n0 = wave * 32;

#pragma unroll
    for (int it = 0; it < 4; ++it) {
        int i = it * 256 + tx;
        int r = i >> 4, ch = i & 15;
        int row = rowbase + r;
        size_t rs = (size_t)((row < NNODE) ? row : NNODE - 1) * H + ch * 8;
        *reinterpret_cast<short8*>(&At[r * 264 + ch * 8]) =
            *reinterpret_cast<const short8*>(&agg[rs]);
        *reinterpret_cast<short8*>(&At[r * 264 + 128 + ch * 8]) =
            *reinterpret_cast<const short8*>(&xdst[rs]);
    }

    short8 bf[8][2];
#pragma unroll
    for (int kt = 0; kt < 8; ++kt) {
        const ushortT* wT = (kt < 4) ? wlT : wrT;
        const int kk = (kt & 3) * 32 + quad * 8;
        bf[kt][0] = *reinterpret_cast<const short8*>(&wT[(n0 + ln) * 128 + kk]);
        bf[kt][1] = *reinterpret_cast<const short8*>(&wT[(n0 + 16 + ln) * 128 + kk]);
    }
    __syncthreads();

    floatx4 acc[4][2] = {};
#pragma unroll
    for (int ms = 0; ms < 4; ++ms) {
#pragma unroll
        for (int kt = 0; kt < 8; ++kt) {
            short8 af = *reinterpret_cast<const short8*>(
                &At[(ms * 16 + ln) * 264 + kt * 32 + quad * 8]);
            acc[ms][0] = __builtin_amdgcn_mfma_f32_16x16x32_bf16(af, bf[kt][0], acc[ms][0], 0, 0, 0);
            acc[ms][1] = __builtin_amdgcn_mfma_f32_16x16x32_bf16(af, bf[kt][1], acc[ms][1], 0, 0, 0);
        }
    }

    const float bl0 = bl[n0 + ln];
    const float bl1 = bl[n0 + 16 + ln];
#pragma unroll
    for (int ms = 0; ms < 4; ++ms) {
#pragma unroll
        for (int r = 0; r < 4; ++r) {
            float v0 = acc[ms][0][r] + bl0;
            float v1 = acc[ms][1][r] + bl1;
            acc[ms][0][r] = v0;
            acc[ms][1][r] = v1;
            float s = v0 * v0 + v1 * v1;
            s += __shfl_xor(s, 1, 64);
            s += __shfl_xor(s, 2, 64);
            s += __shfl_xor(s, 4, 64);
            s += __shfl_xor(s, 8, 64);
            if (ln == 0) part[wave][ms * 16 + quad * 4 + r] = s;
        }
    }
    __syncthreads();
    if (tx < 64) {
        float t = part[0][tx] + part[1][tx] + part[2][tx] + part[3][tx];
        scl[tx] = 1.f / fmaxf(sqrtf(t), 1e-12f);
    }
    __syncthreads();
#pragma unroll
    for (int ms = 0; ms < 4; ++ms) {
#pragma unroll
        for (int r = 0; r < 4; ++r) {
            const int lr = ms * 16 + quad * 4 + r;
            const int row = rowbase + lr;
            if (row < NNODE) {
                const float sc = scl[lr];
                float o0 = fmaxf(acc[ms][0][r] * sc, 0.f) + bf2f(At[lr * 264 + 128 + n0 + ln]);
                float o1 = fmaxf(acc[ms][1][r] * sc, 0.f) + bf2f(At[lr * 264 + 128 + n0 + 16 + ln]);
                out[(size_t)row * H + n0 + ln] = f2bf(o0);
                out[(size_t)row * H + n0 + 16 + ln] = f2bf(o1);
            }
        }
    }
}

// ---------------------------------------------------------------------------
// D9: head, 64 rows/block (w1 fragments in registers)
// ---------------------------------------------------------------------------
__global__ void head_kernel(const ushortT* __restrict__ hu, const ushortT* __restrict__ w1T,
                            const float* __restrict__ b1, const float* __restrict__ w2,
                            const float* __restrict__ b2, float* __restrict__ out) {
    __shared__ ushortT hs[64 * 136];
    __shared__ float zs[64 * 72];
    const int tx = threadIdx.x;
    const int rowbase = blockIdx.x * 64;
    const int wave = tx >> 6, lane = tx & 63;
    const int ln = lane & 15, quad = lane >> 4;
#pragma unroll
    for (int it = 0; it < 4; ++it) {
        int i = it * 256 + tx;
        int r = i >> 4, ch = i & 15;
        int row = rowbase + r;
        size_t rs = (size_t)((row < NNODE) ? row : NNODE - 1) * H + ch * 8;
        *reinterpret_cast<short8*>(&hs[r * 136 + ch * 8]) =
            *reinterpret_cast<const short8*>(&hu[rs]);
    }
    short8 bf[4];
#pragma unroll
    for (int kt = 0; kt < 4; ++kt)
        bf[kt] = *reinterpret_cast<const short8*>(&w1T[(wave * 16 + ln) * 128 + kt * 32 + quad * 8]);
    __syncthreads();
    floatx4 acc[4] = {};
#pragma unroll
    for (int ms = 0; ms < 4; ++ms) {
#pragma unroll
        for (int kt = 0; kt < 4; ++kt) {
            short8 af = *reinterpret_cast<const short8*>(
                &hs[(ms * 16 + ln) * 136 + kt * 32 + quad * 8]);
            acc[ms] = __builtin_amdgcn_mfma_f32_16x16x32_bf16(af, bf[kt], acc[ms], 0, 0, 0);
        }
    }
    const float bv = b1[wave * 16 + ln];
#pragma unroll
    for (int ms = 0; ms < 4; ++ms)
#pragma unroll
        for (int r = 0; r < 4; ++r)
            zs[(ms * 16 + quad * 4 + r) * 72 + wave * 16 + ln] = fmaxf(acc[ms][r] + bv, 0.f);
    __syncthreads();
#pragma unroll
    for (int u = 0; u < 2; ++u) {
        int i = tx * 2 + u;
        int r = i >> 3, c = i & 7;
        int row = rowbase + r;
        if (row < NNODE) {
            float a = b2[c];
#pragma unroll 8
            for (int k = 0; k < 64; ++k) a += zs[r * 72 + k] * w2[k * 8 + c];
            out[(size_t)row * 8 + c] = a;
        }
    }
}

// ---------------------------------------------------------------------------
extern "C" void kernel_launch(void* const* d_in, const int* in_sizes, int n_in,
                              void* d_out, int out_size, void* d_ws, size_t ws_size,
                              hipStream_t stream) {
    const float* x_user     = (const float*)d_in[0];
    const float* x_item     = (const float*)d_in[1];
    const int*   ei_u2i     = (const int*)d_in[2];
    const int*   ei_i2u     = (const int*)d_in[3];
    const float* enc_user_w = (const float*)d_in[4];
    const float* enc_user_b = (const float*)d_in[5];
    const float* enc_item_w = (const float*)d_in[6];
    const float* enc_item_b = (const float*)d_in[7];
    const float* W[12];
    for (int i = 0; i < 12; ++i) W[i] = (const float*)d_in[8 + i];
    const float* head_w1 = (const float*)d_in[20];
    const float* head_b1 = (const float*)d_in[21];
    const float* head_w2 = (const float*)d_in[22];
    const float* head_b2 = (const float*)d_in[23];
    float* out = (float*)d_out;

    const size_t S = (size_t)NNODE * H;
    ushortT* huA  = (ushortT*)d_ws;
    ushortT* huB  = huA + S;
    ushortT* hiA  = huB + S;
    ushortT* hiB  = hiA + S;
    ushortT* wT   = hiB + S;                  // 151552 bf16
    int*    scanH_i = (int*)(wT + 151552);    // [SCANH_N]
    int*    scanH_u = scanH_i + SCANH_N;
    int*    bsum_i  = scanH_u + SCANH_N;      // [256] raw block sums
    int*    bsum_u  = bsum_i + 256;
    int*    off_i   = bsum_u + 256;           // [NNODE+1]
    int*    off_u   = off_i + NNODE + 1;
    uintT*  stage_i = (uintT*)(off_u + NNODE + 1);  // [NEDGE]
    uintT*  stage_u = stage_i + NEDGE;
    ushortT* src_i  = (ushortT*)(stage_u + NEDGE);  // [NEDGE] u16
    ushortT* src_u  = src_i + NEDGE;
    ushortT* aggI   = src_u + NEDGE;          // [S]
    ushortT* aggU   = aggI + S;               // [S]

    const ushortT* wTeu = wT + 131072;
    const ushortT* wTei = wT + 139264;
    const ushortT* w1T  = wT + 143360;

    // D1: weight converts + edge histograms
    setup_kernel<<<592 + 2 * BCH, 256, 0, stream>>>(
        W[0], W[2], W[3], W[5], W[6], W[8], W[9], W[11],
        enc_user_w, enc_item_w, head_w1, wT,
        ei_u2i, ei_i2u, scanH_i, scanH_u);

    // D2: encoders + scanH scans
    encscan_kernel<<<2 * NBLK16 + 2 * NBS, 256, 0, stream>>>(
        x_user, wTeu, enc_user_b, x_item, wTei, enc_item_b, huA, hiA,
        scanH_i, bsum_i, scanH_u, bsum_u);

    // D3/D4: locality-preserving scatter, then per-bucket sort -> CSR
    scatterA_kernel<<<2 * BCH, 256, 0, stream>>>(ei_u2i, ei_i2u, scanH_i, bsum_i,
                                                 scanH_u, bsum_u, stage_i, stage_u);
    passB_kernel<<<2 * NBUK, 256, 0, stream>>>(stage_i, scanH_i, bsum_i, src_i, off_i,
                                               stage_u, scanH_u, bsum_u, src_u, off_u);

    // layer 0
    gather2_kernel<<<2 * GBLK, 256, 0, stream>>>(huA, src_i, off_i, aggI,
                                                 hiA, src_u, off_u, aggU);
    sageM_kernel<<<2 * SAGEB, 256, 0, stream>>>(
        aggI, hiA, wT + 0 * 16384, W[1], wT + 1 * 16384, hiB,
        aggU, huA, wT + 2 * 16384, W[4], wT + 3 * 16384, huB);

    // layer 1
    gather2_kernel<<<2 * GBLK, 256, 0, stream>>>(huB, src_i, off_i, aggI,
                                                 hiB, src_u, off_u, aggU);
    sageM_kernel<<<2 * SAGEB, 256, 0, stream>>>(
        aggI, hiB, wT + 4 * 16384, W[7], wT + 5 * 16384, hiA,
        aggU, huB, wT + 6 * 16384, W[10], wT + 7 * 16384, huA);

    head_kernel<<<SAGEB, 256, 0, stream>>>(huA, w1T, head_b1, head_w2, head_b2, out);
}

// Round 12
// 323.112 us; speedup vs baseline: 1.0681x; 1.0366x over previous
//
#include <hip/hip_runtime.h>
#include <math.h>

#define H 128
#define NNODE 50000
#define NEDGE 800000
#define NBLK16 3125      // NNODE / 16
#define NBUK 782         // buckets of 64 dst nodes: ceil(50000/64)
#define BCH 256          // edge chunks per type
#define CHUNK 3125       // NEDGE / BCH
#define SCANH_N 200192   // NBUK * BCH
#define NBS 196          // scan blocks per array (1024 elems each)
#define BCAP 1536        // max edges per bucket (mean 1024)
#define GBLK 12500       // gather blocks per direction (4 rows/block, 1 row/wave)
#define SAGEB 782        // sage blocks per direction (64 rows/block)

typedef unsigned short ushortT;
typedef unsigned int uintT;
typedef __attribute__((ext_vector_type(8))) short short8;
typedef __attribute__((ext_vector_type(4))) float floatx4;
typedef __attribute__((ext_vector_type(2))) float float2v;

static __device__ __forceinline__ float bf2f(ushortT u) {
    union { uintT i; float f; } c; c.i = ((uintT)u) << 16; return c.f;
}
static __device__ __forceinline__ ushortT f2bf(float f) {
    union { float f; uintT i; } c; c.f = f;
    uintT lsb = (c.i >> 16) & 1;
    c.i += 0x7fffu + lsb;          // round-to-nearest-even
    return (ushortT)(c.i >> 16);
}
static __device__ __forceinline__ float lo2f(uintT v) {
    union { uintT i; float f; } c; c.i = v << 16; return c.f;
}
static __device__ __forceinline__ float hi2f(uintT v) {
    union { uintT i; float f; } c; c.i = v & 0xffff0000u; return c.f;
}
static __device__ __forceinline__ uintT pack2(float a, float b) {
    return (uintT)f2bf(a) | ((uintT)f2bf(b) << 16);
}
// fp8 e4m3 (OCP) HW converters
static __device__ __forceinline__ float2v f8lo(uintT v) {
    return __builtin_amdgcn_cvt_pk_f32_fp8((int)v, false);
}
static __device__ __forceinline__ float2v f8hi(uintT v) {
    return __builtin_amdgcn_cvt_pk_f32_fp8((int)v, true);
}
static __device__ __forceinline__ uint2 pk8(const float f[8]) {
    int a = __builtin_amdgcn_cvt_pk_fp8_f32(f[0], f[1], 0, false);
    a = __builtin_amdgcn_cvt_pk_fp8_f32(f[2], f[3], a, true);
    int b = __builtin_amdgcn_cvt_pk_fp8_f32(f[4], f[5], 0, false);
    b = __builtin_amdgcn_cvt_pk_fp8_f32(f[6], f[7], b, true);
    uint2 r; r.x = (uintT)a; r.y = (uintT)b;
    return r;
}

// ---------------------------------------------------------------------------
// D1: weight convert+transpose (blocks 0..591) + edge histograms (592..1103)
// ---------------------------------------------------------------------------
__global__ void setup_kernel(const float* __restrict__ s0, const float* __restrict__ s1,
                             const float* __restrict__ s2, const float* __restrict__ s3,
                             const float* __restrict__ s4, const float* __restrict__ s5,
                             const float* __restrict__ s6, const float* __restrict__ s7,
                             const float* __restrict__ seu, const float* __restrict__ sei,
                             const float* __restrict__ sw1, ushortT* __restrict__ wT,
                             const int* __restrict__ e0, const int* __restrict__ e1,
                             int* __restrict__ scanH0, int* __restrict__ scanH1) {
    __shared__ int hist[NBUK];
    const int b = blockIdx.x, t = threadIdx.x;
    if (b < 512) {
        const int m = b >> 6;
        const float* s = (m == 0) ? s0 : (m == 1) ? s1 : (m == 2) ? s2 : (m == 3) ? s3
                       : (m == 4) ? s4 : (m == 5) ? s5 : (m == 6) ? s6 : s7;
        int i = (b & 63) * 256 + t;
        int k = i >> 7, c = i & 127;
        wT[m * 16384 + c * 128 + k] = f2bf(s[k * 128 + c]);
    } else if (b < 544) {
        int i = (b - 512) * 256 + t;
        int k = i >> 7, c = i & 127;
        wT[131072 + c * 64 + k] = f2bf(seu[k * 128 + c]);
    } else if (b < 560) {
        int i = (b - 544) * 256 + t;
        int k = i >> 7, c = i & 127;
        wT[139264 + c * 32 + k] = f2bf(sei[k * 128 + c]);
    } else if (b < 592) {
        int i = (b - 560) * 256 + t;
        int k = i >> 6, c = i & 63;
        wT[143360 + c * 128 + k] = f2bf(sw1[k * 64 + c]);
    } else {
        const int hb = b - 592;
        const bool first = hb < BCH;
        const int c = first ? hb : hb - BCH;
        const int* edst = (first ? e0 : e1) + NEDGE + c * CHUNK;
        int* scanH = first ? scanH0 : scanH1;
        for (int i = t; i < NBUK; i += 256) hist[i] = 0;
        __syncthreads();
        for (int e = t; e < CHUNK; e += 256) atomicAdd(&hist[edst[e] >> 6], 1);
        __syncthreads();
        for (int i = t; i < NBUK; i += 256) scanH[i * BCH + c] = hist[i];
    }
}

// ---------------------------------------------------------------------------
// D2: merged encoders (MFMA, blocks [0,6250), bf16 + fp8 outputs)
//     + scanH exclusive scans (rest)
// ---------------------------------------------------------------------------
__global__ void encscan_kernel(const float* __restrict__ xu, const ushortT* __restrict__ wTu,
                               const float* __restrict__ bu,
                               const float* __restrict__ xi, const ushortT* __restrict__ wTi,
                               const float* __restrict__ bi,
                               ushortT* __restrict__ outu, ushortT* __restrict__ outi,
                               uint2* __restrict__ out8u, uint2* __restrict__ out8i,
                               int* __restrict__ scanH0, int* __restrict__ bsum0,
                               int* __restrict__ scanH1, int* __restrict__ bsum1) {
    __shared__ ushortT xs[16 * 72];
    __shared__ ushortT os[16 * 128];
    __shared__ int tmp[256];
    const int tx = threadIdx.x;
    if (blockIdx.x >= 2 * NBLK16) {
        const int sb = blockIdx.x - 2 * NBLK16;
        const bool first = sb < NBS;
        const int blk = first ? sb : sb - NBS;
        int* arr = first ? scanH0 : scanH1;
        int* bsum = first ? bsum0 : bsum1;
        const int base = blk * 1024;
        int v[4];
        int s = 0;
#pragma unroll
        for (int k = 0; k < 4; ++k) {
            int i = base + tx * 4 + k;
            v[k] = (i < SCANH_N) ? arr[i] : 0;
            s += v[k];
        }
        tmp[tx] = s;
        __syncthreads();
        for (int o = 1; o < 256; o <<= 1) {
            int t = (tx >= o) ? tmp[tx - o] : 0;
            __syncthreads();
            tmp[tx] += t;
            __syncthreads();
        }
        int excl = (tx == 0) ? 0 : tmp[tx - 1];
#pragma unroll
        for (int k = 0; k < 4; ++k) {
            int i = base + tx * 4 + k;
            if (i < SCANH_N) arr[i] = excl;
            excl += v[k];
        }
        if (tx == 255) bsum[blk] = tmp[255];
        return;
    }
    const bool user = blockIdx.x < NBLK16;
    const int blk = user ? blockIdx.x : blockIdx.x - NBLK16;
    const int K = user ? 64 : 32;
    const int kshift = user ? 6 : 5;
    const int stride = K + 8;
    const float* x = user ? xu : xi;
    const ushortT* wT = user ? wTu : wTi;
    const float* bias = user ? bu : bi;
    ushortT* out = user ? outu : outi;
    uint2* out8 = user ? out8u : out8i;
    const int rowbase = blk * 16;
    {
        int i = tx * 4;
        if (i < 16 * K) {
            const float4 v = *reinterpret_cast<const float4*>(&x[(size_t)rowbase * K + i]);
            int r = i >> kshift, c = i & (K - 1);
            uint2 w;
            w.x = pack2(v.x, v.y);
            w.y = pack2(v.z, v.w);
            *reinterpret_cast<uint2*>(&xs[r * stride + c]) = w;
        }
    }
    __syncthreads();
    const int wave = tx >> 6, lane = tx & 63;
    const int ln = lane & 15, quad = lane >> 4;
    const int n0 = wave * 32;
    floatx4 acc0 = {0.f, 0.f, 0.f, 0.f};
    floatx4 acc1 = {0.f, 0.f, 0.f, 0.f};
    for (int k0 = 0; k0 < K; k0 += 32) {
        short8 af = *reinterpret_cast<const short8*>(&xs[ln * stride + k0 + quad * 8]);
        short8 b0 = *reinterpret_cast<const short8*>(&wT[(n0 + ln) * K + k0 + quad * 8]);
        short8 b1 = *reinterpret_cast<const short8*>(&wT[(n0 + 16 + ln) * K + k0 + quad * 8]);
        acc0 = __builtin_amdgcn_mfma_f32_16x16x32_bf16(af, b0, acc0, 0, 0, 0);
        acc1 = __builtin_amdgcn_mfma_f32_16x16x32_bf16(af, b1, acc1, 0, 0, 0);
    }
    const float b0v = bias[n0 + ln], b1v = bias[n0 + 16 + ln];
#pragma unroll
    for (int r = 0; r < 4; ++r) {
        int lr = quad * 4 + r;
        int row = rowbase + lr;
        ushortT v0 = f2bf(fmaxf(acc0[r] + b0v, 0.f));
        ushortT v1 = f2bf(fmaxf(acc1[r] + b1v, 0.f));
        out[(size_t)row * H + n0 + ln] = v0;
        out[(size_t)row * H + n0 + 16 + ln] = v1;
        os[lr * 128 + n0 + ln] = v0;
        os[lr * 128 + n0 + 16 + ln] = v1;
    }
    __syncthreads();
    {   // fp8 shadow copy: 2048 elems, 8 per thread, coalesced
        int i = tx * 8;
        int r = i >> 7, c = i & 127;
        uint4 w = *reinterpret_cast<const uint4*>(&os[r * 128 + c]);
        float f[8] = {lo2f(w.x), hi2f(w.x), lo2f(w.y), hi2f(w.y),
                      lo2f(w.z), hi2f(w.z), lo2f(w.w), hi2f(w.w)};
        out8[(size_t)(rowbase + r) * 16 + (c >> 3)] = pk8(f);
    }
}

// 256-thread LDS exclusive scan of NBS raw block sums into bpre[256].
static __device__ __forceinline__ void bsum_scan(const int* __restrict__ bsum, int* bpre, int tx) {
    int v = (tx < NBS) ? bsum[tx] : 0;
    bpre[tx] = v;
    __syncthreads();
    for (int o = 1; o < 256; o <<= 1) {
        int t = (tx >= o) ? bpre[tx - o] : 0;
        __syncthreads();
        bpre[tx] += t;
        __syncthreads();
    }
    int excl = (tx == 0) ? 0 : bpre[tx - 1];
    __syncthreads();
    bpre[tx] = excl;
}

// ---------------------------------------------------------------------------
// D3: scatter packed (dst<<16 | src) into per-(bucket,chunk) exclusive ranges
// ---------------------------------------------------------------------------
__global__ void scatterA_kernel(const int* __restrict__ e0, const int* __restrict__ e1,
                                const int* __restrict__ scanH0, const int* __restrict__ bsum0,
                                const int* __restrict__ scanH1, const int* __restrict__ bsum1,
                                uintT* __restrict__ stage0, uintT* __restrict__ stage1) {
    __shared__ int cur[NBUK];
    __shared__ int bpre[256];
    const int tx = threadIdx.x;
    const bool first = blockIdx.x < BCH;
    const int c = first ? blockIdx.x : blockIdx.x - BCH;
    const int* ei = first ? e0 : e1;
    const int* scanH = first ? scanH0 : scanH1;
    const int* bsum = first ? bsum0 : bsum1;
    uintT* stage = first ? stage0 : stage1;

    bsum_scan(bsum, bpre, tx);
    __syncthreads();
    for (int i = tx; i < NBUK; i += 256) {
        int idx = i * BCH + c;
        cur[i] = scanH[idx] + bpre[idx >> 10];
    }
    __syncthreads();
    const int base = c * CHUNK;
    for (int e = tx; e < CHUNK; e += 256) {
        int s = ei[base + e];
        int d = ei[NEDGE + base + e];
        int pos = atomicAdd(&cur[d >> 6], 1);
        stage[pos] = ((uintT)d << 16) | (uintT)s;
    }
}

// ---------------------------------------------------------------------------
// D4: per-bucket local sort by dst; dense u16 srcidx + off[]
// ---------------------------------------------------------------------------
__global__ void passB_kernel(const uintT* __restrict__ stage0, const int* __restrict__ scanH0,
                             const int* __restrict__ bsum0, ushortT* __restrict__ srcidx0,
                             int* __restrict__ off0,
                             const uintT* __restrict__ stage1, const int* __restrict__ scanH1,
                             const int* __restrict__ bsum1, ushortT* __restrict__ srcidx1,
                             int* __restrict__ off1) {
    __shared__ uintT inbuf[BCAP];
    __shared__ ushortT outbuf[BCAP];
    __shared__ int hist[64], scn[64], cur[64];
    __shared__ int bpre[256];
    const int tx = threadIdx.x;
    const bool first = blockIdx.x < NBUK;
    const int b = first ? blockIdx.x : blockIdx.x - NBUK;
    const uintT* stage = first ? stage0 : stage1;
    const int* scanH = first ? scanH0 : scanH1;
    const int* bsum = first ? bsum0 : bsum1;
    ushortT* srcidx = first ? srcidx0 : srcidx1;
    int* off = first ? off0 : off1;

    bsum_scan(bsum, bpre, tx);
    __syncthreads();
    if (tx < 64) hist[tx] = 0;

    const int ib = b * BCH;
    const int base = scanH[ib] + bpre[ib >> 10];
    const int end = (b == NBUK - 1) ? NEDGE : (scanH[ib + BCH] + bpre[(ib + BCH) >> 10]);
    const int size = end - base;

    for (int i = tx; i < size; i += 256) inbuf[i] = stage[base + i];
    __syncthreads();
    for (int i = tx; i < size; i += 256) atomicAdd(&hist[(inbuf[i] >> 16) & 63], 1);
    __syncthreads();
    if (tx == 0) {
        int s = 0;
#pragma unroll
        for (int i = 0; i < 64; ++i) { scn[i] = s; s += hist[i]; }
    }
    __syncthreads();
    if (tx < 64) cur[tx] = scn[tx];
    __syncthreads();
    for (int i = tx; i < size; i += 256) {
        uintT w = inbuf[i];
        int pos = atomicAdd(&cur[(w >> 16) & 63], 1);
        outbuf[pos] = (ushortT)(w & 0xffffu);
    }
    __syncthreads();
    for (int i = tx; i < size; i += 256) srcidx[base + i] = outbuf[i];
    if (tx < 64) {
        int d = b * 64 + tx;
        if (d < NNODE) off[d] = base + scn[tx];
    }
    if (b == NBUK - 1 && tx == 64) off[NNODE] = NEDGE;
}

// ---------------------------------------------------------------------------
// D5/D7: dedicated gather-mean from FP8 source rows (128 B/row — half the
// bytes of bf16; the r9-r11 plateau at ~3.9 TB/s demand was byte-bound).
// One WAVE per dst row; 16-lane group g covers one row via dwordx2; one
// wave-load fetches 4 edges. Row's first 64 indices loaded once (coalesced),
// per-chunk idx via __shfl. Output agg stays bf16 (fp32 accumulate).
// ---------------------------------------------------------------------------
__global__ void gather2_kernel(const uint2* __restrict__ src8A, const ushortT* __restrict__ srcA,
                               const int* __restrict__ offA, ushortT* __restrict__ aggA,
                               const uint2* __restrict__ src8B, const ushortT* __restrict__ srcB,
                               const int* __restrict__ offB, ushortT* __restrict__ aggB) {
    const bool first = blockIdx.x < GBLK;
    const int blk = first ? blockIdx.x : blockIdx.x - GBLK;
    const uint2* srcv = first ? src8A : src8B;
    const ushortT* srcidx = first ? srcA : srcB;
    const int* off = first ? offA : offB;
    ushortT* agg = first ? aggA : aggB;

    const int wave = threadIdx.x >> 6, lane = threadIdx.x & 63;
    const int g = lane >> 4, gl = lane & 15;
    const int row = blk * 4 + wave;
    const int start = off[row];
    const int deg = off[row + 1] - start;
    const ushortT* sidx = srcidx + start;

    // one coalesced load of up to 64 indices into registers
    const int clampi = (deg > 0) ? deg - 1 : 0;
    const int myidx = sidx[(lane < clampi) ? lane : clampi];
    const int degc = (deg < 64) ? deg : 64;

    float2v acc0 = {0.f, 0.f}, acc1 = {0.f, 0.f}, acc2 = {0.f, 0.f}, acc3 = {0.f, 0.f};
    int j = 0;
    for (; j + 16 <= degc; j += 16) {         // unmasked, idx via shuffle
        uint2 v[4];
#pragma unroll
        for (int u = 0; u < 4; ++u) {
            int s = __shfl(myidx, j + u * 4 + g, 64);
            v[u] = srcv[(size_t)s * 16 + gl];
        }
#pragma unroll
        for (int u = 0; u < 4; ++u) {
            acc0 += f8lo(v[u].x);
            acc1 += f8hi(v[u].x);
            acc2 += f8lo(v[u].y);
            acc3 += f8hi(v[u].y);
        }
    }
    if (j < degc) {                           // one masked 16-chunk, 4 loads in flight
        uint2 v[4];
        float m[4];
#pragma unroll
        for (int u = 0; u < 4; ++u) {
            int e = j + u * 4 + g;
            int ee = (e < degc) ? e : degc - 1;
            int s = __shfl(myidx, ee, 64);
            v[u] = srcv[(size_t)s * 16 + gl];
            m[u] = (e < degc) ? 1.f : 0.f;
        }
#pragma unroll
        for (int u = 0; u < 4; ++u) {
            float2v t0 = f8lo(v[u].x), t1 = f8hi(v[u].x);
            float2v t2 = f8lo(v[u].y), t3 = f8hi(v[u].y);
            acc0.x = fmaf(t0.x, m[u], acc0.x); acc0.y = fmaf(t0.y, m[u], acc0.y);
            acc1.x = fmaf(t1.x, m[u], acc1.x); acc1.y = fmaf(t1.y, m[u], acc1.y);
            acc2.x = fmaf(t2.x, m[u], acc2.x); acc2.y = fmaf(t2.y, m[u], acc2.y);
            acc3.x = fmaf(t3.x, m[u], acc3.x); acc3.y = fmaf(t3.y, m[u], acc3.y);
        }
    }
    if (deg > 64) {                           // cold path: P(deg>64) ~ 0
        for (int e0 = 64; e0 < deg; e0 += 4) {
            int e = e0 + g;
            int ec = (e < deg) ? e : deg - 1;
            int s = sidx[ec];
            uint2 v = srcv[(size_t)s * 16 + gl];
            float m = (e < deg) ? 1.f : 0.f;
            float2v t0 = f8lo(v.x), t1 = f8hi(v.x);
            float2v t2 = f8lo(v.y), t3 = f8hi(v.y);
            acc0.x = fmaf(t0.x, m, acc0.x); acc0.y = fmaf(t0.y, m, acc0.y);
            acc1.x = fmaf(t1.x, m, acc1.x); acc1.y = fmaf(t1.y, m, acc1.y);
            acc2.x = fmaf(t2.x, m, acc2.x); acc2.y = fmaf(t2.y, m, acc2.y);
            acc3.x = fmaf(t3.x, m, acc3.x); acc3.y = fmaf(t3.y, m, acc3.y);
        }
    }
#pragma unroll
    for (int o = 16; o <= 32; o <<= 1) {
        acc0.x += __shfl_xor(acc0.x, o, 64); acc0.y += __shfl_xor(acc0.y, o, 64);
        acc1.x += __shfl_xor(acc1.x, o, 64); acc1.y += __shfl_xor(acc1.y, o, 64);
        acc2.x += __shfl_xor(acc2.x, o, 64); acc2.y += __shfl_xor(acc2.y, o, 64);
        acc3.x += __shfl_xor(acc3.x, o, 64); acc3.y += __shfl_xor(acc3.y, o, 64);
    }
    if (lane < 16) {
        const float inv = 1.f / fmaxf((float)deg, 1.f);
        uint4 o;
        o.x = pack2(acc0.x * inv, acc0.y * inv);
        o.y = pack2(acc1.x * inv, acc1.y * inv);
        o.z = pack2(acc2.x * inv, acc2.y * inv);
        o.w = pack2(acc3.x * inv, acc3.y * inv);
        ((uint4*)agg)[(size_t)row * 16 + gl] = o;
    }
}

// ---------------------------------------------------------------------------
// D6/D8: streaming SAGE MFMA, 64 rows/block, B fragments in registers.
//   out = relu( l2norm( [agg | xdst] @ [wl;wr] + bl ) ) + xdst
// Also emits an fp8 shadow copy of out (next layer's gather source).
// ---------------------------------------------------------------------------
__global__ void sageM_kernel(
    const ushortT* __restrict__ aggA, const ushortT* __restrict__ xdstA,
    const ushortT* __restrict__ wlTA, const float* __restrict__ blA,
    const ushortT* __restrict__ wrTA, ushortT* __restrict__ outA, uint2* __restrict__ out8A,
    const ushortT* __restrict__ aggB, const ushortT* __restrict__ xdstB,
    const ushortT* __restrict__ wlTB, const float* __restrict__ blB,
    const ushortT* __restrict__ wrTB, ushortT* __restrict__ outB, uint2* __restrict__ out8B) {
    __shared__ ushortT At[64 * 264];     // 33.8 KB
    __shared__ float part[4][64];
    __shared__ float scl[64];
    const bool first = blockIdx.x < SAGEB;
    const int blk = first ? blockIdx.x : blockIdx.x - SAGEB;
    const ushortT* agg  = first ? aggA  : aggB;
    const ushortT* xdst = first ? xdstA : xdstB;
    const ushortT* wlT  = first ? wlTA  : wlTB;
    const float* bl     = first ? blA   : blB;
    const ushortT* wrT  = first ? wrTA  : wrTB;
    ushortT* out        = first ? outA  : outB;
    uint2* out8         = first ? out8A : out8B;

    const int tx = threadIdx.x;
    const int rowbase = blk * 64;
    const int wave = tx >> 6, lane = tx & 63;
    const int ln = lane & 15, quad = lane >> 4;
    const int n0 = wave * 32;

#pragma unroll
    for (int it = 0; it < 4; ++it) {
        int i = it * 256 + tx;
        int r = i >> 4, ch = i & 15;
        int row = rowbase + r;
        size_t rs = (size_t)((row < NNODE) ? row : NNODE - 1) * H + ch * 8;
        *reinterpret_cast<short8*>(&At[r * 264 + ch * 8]) =
            *reinterpret_cast<const short8*>(&agg[rs]);
        *reinterpret_cast<short8*>(&At[r * 264 + 128 + ch * 8]) =
            *reinterpret_cast<const short8*>(&xdst[rs]);
    }

    short8 bf[8][2];
#pragma unroll
    for (int kt = 0; kt < 8; ++kt) {
        const ushortT* wT = (kt < 4) ? wlT : wrT;
        const int kk = (kt & 3) * 32 + quad * 8;
        bf[kt][0] = *reinterpret_cast<const short8*>(&wT[(n0 + ln) * 128 + kk]);
        bf[kt][1] = *reinterpret_cast<const short8*>(&wT[(n0 + 16 + ln) * 128 + kk]);
    }
    __syncthreads();

    floatx4 acc[4][2] = {};
#pragma unroll
    for (int ms = 0; ms < 4; ++ms) {
#pragma unroll
        for (int kt = 0; kt < 8; ++kt) {
            short8 af = *reinterpret_cast<const short8*>(
                &At[(ms * 16 + ln) * 264 + kt * 32 + quad * 8]);
            acc[ms][0] = __builtin_amdgcn_mfma_f32_16x16x32_bf16(af, bf[kt][0], acc[ms][0], 0, 0, 0);
            acc[ms][1] = __builtin_amdgcn_mfma_f32_16x16x32_bf16(af, bf[kt][1], acc[ms][1], 0, 0, 0);
        }
    }

    const float bl0 = bl[n0 + ln];
    const float bl1 = bl[n0 + 16 + ln];
#pragma unroll
    for (int ms = 0; ms < 4; ++ms) {
#pragma unroll
        for (int r = 0; r < 4; ++r) {
            float v0 = acc[ms][0][r] + bl0;
            float v1 = acc[ms][1][r] + bl1;
            acc[ms][0][r] = v0;
            acc[ms][1][r] = v1;
            float s = v0 * v0 + v1 * v1;
            s += __shfl_xor(s, 1, 64);
            s += __shfl_xor(s, 2, 64);
            s += __shfl_xor(s, 4, 64);
            s += __shfl_xor(s, 8, 64);
            if (ln == 0) part[wave][ms * 16 + quad * 4 + r] = s;
        }
    }
    __syncthreads();
    if (tx < 64) {
        float t = part[0][tx] + part[1][tx] + part[2][tx] + part[3][tx];
        scl[tx] = 1.f / fmaxf(sqrtf(t), 1e-12f);
    }
    __syncthreads();
#pragma unroll
    for (int ms = 0; ms < 4; ++ms) {
#pragma unroll
        for (int r = 0; r < 4; ++r) {
            const int lr = ms * 16 + quad * 4 + r;
            const int row = rowbase + lr;
            const float sc = scl[lr];
            float o0 = fmaxf(acc[ms][0][r] * sc, 0.f) + bf2f(At[lr * 264 + 128 + n0 + ln]);
            float o1 = fmaxf(acc[ms][1][r] * sc, 0.f) + bf2f(At[lr * 264 + 128 + n0 + 16 + ln]);
            ushortT b0 = f2bf(o0), b1 = f2bf(o1);
            if (row < NNODE) {
                out[(size_t)row * H + n0 + ln] = b0;
                out[(size_t)row * H + n0 + 16 + ln] = b1;
            }
            // stage into the (consumed) agg half of At for the fp8 pass
            At[lr * 264 + n0 + ln] = b0;
            At[lr * 264 + n0 + 16 + ln] = b1;
        }
    }
    __syncthreads();
    // fp8 shadow copy: 8192 elems, 32/thread, coalesced
#pragma unroll
    for (int it = 0; it < 4; ++it) {
        int i = it * 2048 + tx * 8;
        int r = i >> 7, c = i & 127;
        int row = rowbase + r;
        if (row < NNODE) {
            uint4 w = *reinterpret_cast<const uint4*>(&At[r * 264 + c]);
            float f[8] = {lo2f(w.x), hi2f(w.x), lo2f(w.y), hi2f(w.y),
                          lo2f(w.z), hi2f(w.z), lo2f(w.w), hi2f(w.w)};
            out8[(size_t)row * 16 + (c >> 3)] = pk8(f);
        }
    }
}

// ---------------------------------------------------------------------------
// D9: head, 64 rows/block (w1 fragments in registers)
// ---------------------------------------------------------------------------
__global__ void head_kernel(const ushortT* __restrict__ hu, const ushortT* __restrict__ w1T,
                            const float* __restrict__ b1, const float* __restrict__ w2,
                            const float* __restrict__ b2, float* __restrict__ out) {
    __shared__ ushortT hs[64 * 136];
    __shared__ float zs[64 * 72];
    const int tx = threadIdx.x;
    const int rowbase = blockIdx.x * 64;
    const int wave = tx >> 6, lane = tx & 63;
    const int ln = lane & 15, quad = lane >> 4;
#pragma unroll
    for (int it = 0; it < 4; ++it) {
        int i = it * 256 + tx;
        int r = i >> 4, ch = i & 15;
        int row = rowbase + r;
        size_t rs = (size_t)((row < NNODE) ? row : NNODE - 1) * H + ch * 8;
        *reinterpret_cast<short8*>(&hs[r * 136 + ch * 8]) =
            *reinterpret_cast<const short8*>(&hu[rs]);
    }
    short8 bf[4];
#pragma unroll
    for (int kt = 0; kt < 4; ++kt)
        bf[kt] = *reinterpret_cast<const short8*>(&w1T[(wave * 16 + ln) * 128 + kt * 32 + quad * 8]);
    __syncthreads();
    floatx4 acc[4] = {};
#pragma unroll
    for (int ms = 0; ms < 4; ++ms) {
#pragma unroll
        for (int kt = 0; kt < 4; ++kt) {
            short8 af = *reinterpret_cast<const short8*>(
                &hs[(ms * 16 + ln) * 136 + kt * 32 + quad * 8]);
            acc[ms] = __builtin_amdgcn_mfma_f32_16x16x32_bf16(af, bf[kt], acc[ms], 0, 0, 0);
        }
    }
    const float bv = b1[wave * 16 + ln];
#pragma unroll
    for (int ms = 0; ms < 4; ++ms)
#pragma unroll
        for (int r = 0; r < 4; ++r)
            zs[(ms * 16 + quad * 4 + r) * 72 + wave * 16 + ln] = fmaxf(acc[ms][r] + bv, 0.f);
    __syncthreads();
#pragma unroll
    for (int u = 0; u < 2; ++u) {
        int i = tx * 2 + u;
        int r = i >> 3, c = i & 7;
        int row = rowbase + r;
        if (row < NNODE) {
            float a = b2[c];
#pragma unroll 8
            for (int k = 0; k < 64; ++k) a += zs[r * 72 + k] * w2[k * 8 + c];
            out[(size_t)row * 8 + c] = a;
        }
    }
}

// ---------------------------------------------------------------------------
extern "C" void kernel_launch(void* const* d_in, const int* in_sizes, int n_in,
                              void* d_out, int out_size, void* d_ws, size_t ws_size,
                              hipStream_t stream) {
    const float* x_user     = (const float*)d_in[0];
    const float* x_item     = (const float*)d_in[1];
    const int*   ei_u2i     = (const int*)d_in[2];
    const int*   ei_i2u     = (const int*)d_in[3];
    const float* enc_user_w = (const float*)d_in[4];
    const float* enc_user_b = (const float*)d_in[5];
    const float* enc_item_w = (const float*)d_in[6];
    const float* enc_item_b = (const float*)d_in[7];
    const float* W[12];
    for (int i = 0; i < 12; ++i) W[i] = (const float*)d_in[8 + i];
    const float* head_w1 = (const float*)d_in[20];
    const float* head_b1 = (const float*)d_in[21];
    const float* head_w2 = (const float*)d_in[22];
    const float* head_b2 = (const float*)d_in[23];
    float* out = (float*)d_out;

    const size_t S = (size_t)NNODE * H;
    ushortT* huA  = (ushortT*)d_ws;
    ushortT* huB  = huA + S;
    ushortT* hiA  = huB + S;
    ushortT* hiB  = hiA + S;
    ushortT* wT   = hiB + S;                  // 151552 bf16
    int*    scanH_i = (int*)(wT + 151552);    // [SCANH_N]
    int*    scanH_u = scanH_i + SCANH_N;
    int*    bsum_i  = scanH_u + SCANH_N;      // [256] raw block sums
    int*    bsum_u  = bsum_i + 256;
    int*    off_i   = bsum_u + 256;           // [NNODE+1]
    int*    off_u   = off_i + NNODE + 1;
    uintT*  stage_i = (uintT*)(off_u + NNODE + 1);  // [NEDGE]
    uintT*  stage_u = stage_i + NEDGE;
    ushortT* src_i  = (ushortT*)(stage_u + NEDGE);  // [NEDGE] u16
    ushortT* src_u  = src_i + NEDGE;
    ushortT* aggI   = src_u + NEDGE;          // [S]
    ushortT* aggU   = aggI + S;               // [S]
    uint2*  hu8A    = (uint2*)(aggU + S);     // fp8 shadows: NNODE*128 B each
    uint2*  hi8A    = hu8A + (size_t)NNODE * 16;
    uint2*  hu8B    = hi8A + (size_t)NNODE * 16;
    uint2*  hi8B    = hu8B + (size_t)NNODE * 16;

    const ushortT* wTeu = wT + 131072;
    const ushortT* wTei = wT + 139264;
    const ushortT* w1T  = wT + 143360;

    // D1: weight converts + edge histograms
    setup_kernel<<<592 + 2 * BCH, 256, 0, stream>>>(
        W[0], W[2], W[3], W[5], W[6], W[8], W[9], W[11],
        enc_user_w, enc_item_w, head_w1, wT,
        ei_u2i, ei_i2u, scanH_i, scanH_u);

    // D2: encoders (bf16 + fp8 out) + scanH scans
    encscan_kernel<<<2 * NBLK16 + 2 * NBS, 256, 0, stream>>>(
        x_user, wTeu, enc_user_b, x_item, wTei, enc_item_b, huA, hiA,
        hu8A, hi8A, scanH_i, bsum_i, scanH_u, bsum_u);

    // D3/D4: locality-preserving scatter, then per-bucket sort -> CSR
    scatterA_kernel<<<2 * BCH, 256, 0, stream>>>(ei_u2i, ei_i2u, scanH_i, bsum_i,
                                                 scanH_u, bsum_u, stage_i, stage_u);
    passB_kernel<<<2 * NBUK, 256, 0, stream>>>(stage_i, scanH_i, bsum_i, src_i, off_i,
                                               stage_u, scanH_u, bsum_u, src_u, off_u);

    // layer 0 (gather reads fp8 shadows of huA/hiA)
    gather2_kernel<<<2 * GBLK, 256, 0, stream>>>(hu8A, src_i, off_i, aggI,
                                                 hi8A, src_u, off_u, aggU);
    sageM_kernel<<<2 * SAGEB, 256, 0, stream>>>(
        aggI, hiA, wT + 0 * 16384, W[1], wT + 1 * 16384, hiB, hi8B,
        aggU, huA, wT + 2 * 16384, W[4], wT + 3 * 16384, huB, hu8B);

    // layer 1 (gather reads fp8 shadows of huB/hiB; L1 fp8 outs are dumped)
    gather2_kernel<<<2 * GBLK, 256, 0, stream>>>(hu8B, src_i, off_i, aggI,
                                                 hi8B, src_u, off_u, aggU);
    sageM_kernel<<<2 * SAGEB, 256, 0, stream>>>(
        aggI, hiB, wT + 4 * 16384, W[7], wT + 5 * 16384, hiA, hi8A,
        aggU, huB, wT + 6 * 16384, W[10], wT + 7 * 16384, huA, hu8A);

    head_kernel<<<SAGEB, 256, 0, stream>>>(huA, w1T, head_b1, head_w2, head_b2, out);
}

// Round 13
// 291.719 us; speedup vs baseline: 1.1830x; 1.1076x over previous
//
#include <hip/hip_runtime.h>
#include <math.h>

#define H 128
#define NNODE 50000
#define NEDGE 800000
#define NBLK16 3125      // NNODE / 16
#define NBUK 782         // buckets of 64 dst nodes: ceil(50000/64)
#define BCH 256          // edge chunks per type
#define CHUNK 3125       // NEDGE / BCH
#define SCANH_N 200192   // NBUK * BCH
#define NBS 196          // scan blocks per array (1024 elems each)
#define BCAP 1536        // max edges per bucket (mean 1024)
#define GBLK 12500       // gather blocks per direction (4 rows/block, 1 row/wave)
#define SAGEB 782        // sage blocks per direction (64 rows/block)

typedef unsigned short ushortT;
typedef unsigned int uintT;
typedef __attribute__((ext_vector_type(8))) short short8;
typedef __attribute__((ext_vector_type(4))) float floatx4;
typedef __attribute__((ext_vector_type(2))) float float2v;

static __device__ __forceinline__ float bf2f(ushortT u) {
    union { uintT i; float f; } c; c.i = ((uintT)u) << 16; return c.f;
}
static __device__ __forceinline__ ushortT f2bf(float f) {
    union { float f; uintT i; } c; c.f = f;
    uintT lsb = (c.i >> 16) & 1;
    c.i += 0x7fffu + lsb;          // round-to-nearest-even
    return (ushortT)(c.i >> 16);
}
static __device__ __forceinline__ float lo2f(uintT v) {
    union { uintT i; float f; } c; c.i = v << 16; return c.f;
}
static __device__ __forceinline__ float hi2f(uintT v) {
    union { uintT i; float f; } c; c.i = v & 0xffff0000u; return c.f;
}
static __device__ __forceinline__ uintT pack2(float a, float b) {
    return (uintT)f2bf(a) | ((uintT)f2bf(b) << 16);
}
// fp8 e4m3 (OCP) HW converters
static __device__ __forceinline__ float2v f8lo(uintT v) {
    return __builtin_amdgcn_cvt_pk_f32_fp8((int)v, false);
}
static __device__ __forceinline__ float2v f8hi(uintT v) {
    return __builtin_amdgcn_cvt_pk_f32_fp8((int)v, true);
}
static __device__ __forceinline__ uint2 pk8(const float f[8]) {
    int a = __builtin_amdgcn_cvt_pk_fp8_f32(f[0], f[1], 0, false);
    a = __builtin_amdgcn_cvt_pk_fp8_f32(f[2], f[3], a, true);
    int b = __builtin_amdgcn_cvt_pk_fp8_f32(f[4], f[5], 0, false);
    b = __builtin_amdgcn_cvt_pk_fp8_f32(f[6], f[7], b, true);
    uint2 r; r.x = (uintT)a; r.y = (uintT)b;
    return r;
}

// ---------------------------------------------------------------------------
// D1: weight convert+transpose (blocks 0..591) + edge histograms (592..1103)
// ---------------------------------------------------------------------------
__global__ void setup_kernel(const float* __restrict__ s0, const float* __restrict__ s1,
                             const float* __restrict__ s2, const float* __restrict__ s3,
                             const float* __restrict__ s4, const float* __restrict__ s5,
                             const float* __restrict__ s6, const float* __restrict__ s7,
                             const float* __restrict__ seu, const float* __restrict__ sei,
                             const float* __restrict__ sw1, ushortT* __restrict__ wT,
                             const int* __restrict__ e0, const int* __restrict__ e1,
                             int* __restrict__ scanH0, int* __restrict__ scanH1) {
    __shared__ int hist[NBUK];
    const int b = blockIdx.x, t = threadIdx.x;
    if (b < 512) {
        const int m = b >> 6;
        const float* s = (m == 0) ? s0 : (m == 1) ? s1 : (m == 2) ? s2 : (m == 3) ? s3
                       : (m == 4) ? s4 : (m == 5) ? s5 : (m == 6) ? s6 : s7;
        int i = (b & 63) * 256 + t;
        int k = i >> 7, c = i & 127;
        wT[m * 16384 + c * 128 + k] = f2bf(s[k * 128 + c]);
    } else if (b < 544) {
        int i = (b - 512) * 256 + t;
        int k = i >> 7, c = i & 127;
        wT[131072 + c * 64 + k] = f2bf(seu[k * 128 + c]);
    } else if (b < 560) {
        int i = (b - 544) * 256 + t;
        int k = i >> 7, c = i & 127;
        wT[139264 + c * 32 + k] = f2bf(sei[k * 128 + c]);
    } else if (b < 592) {
        int i = (b - 560) * 256 + t;
        int k = i >> 6, c = i & 63;
        wT[143360 + c * 128 + k] = f2bf(sw1[k * 64 + c]);
    } else {
        const int hb = b - 592;
        const bool first = hb < BCH;
        const int c = first ? hb : hb - BCH;
        const int* edst = (first ? e0 : e1) + NEDGE + c * CHUNK;
        int* scanH = first ? scanH0 : scanH1;
        for (int i = t; i < NBUK; i += 256) hist[i] = 0;
        __syncthreads();
        for (int e = t; e < CHUNK; e += 256) atomicAdd(&hist[edst[e] >> 6], 1);
        __syncthreads();
        for (int i = t; i < NBUK; i += 256) scanH[i * BCH + c] = hist[i];
    }
}

// ---------------------------------------------------------------------------
// D2: merged encoders (MFMA, blocks [0,6250), bf16 + fp8 outputs)
//     + scanH exclusive scans (rest)
// ---------------------------------------------------------------------------
__global__ void encscan_kernel(const float* __restrict__ xu, const ushortT* __restrict__ wTu,
                               const float* __restrict__ bu,
                               const float* __restrict__ xi, const ushortT* __restrict__ wTi,
                               const float* __restrict__ bi,
                               ushortT* __restrict__ outu, ushortT* __restrict__ outi,
                               uint2* __restrict__ out8u, uint2* __restrict__ out8i,
                               int* __restrict__ scanH0, int* __restrict__ bsum0,
                               int* __restrict__ scanH1, int* __restrict__ bsum1) {
    __shared__ ushortT xs[16 * 72];
    __shared__ ushortT os[16 * 128];
    __shared__ int tmp[256];
    const int tx = threadIdx.x;
    if (blockIdx.x >= 2 * NBLK16) {
        const int sb = blockIdx.x - 2 * NBLK16;
        const bool first = sb < NBS;
        const int blk = first ? sb : sb - NBS;
        int* arr = first ? scanH0 : scanH1;
        int* bsum = first ? bsum0 : bsum1;
        const int base = blk * 1024;
        int v[4];
        int s = 0;
#pragma unroll
        for (int k = 0; k < 4; ++k) {
            int i = base + tx * 4 + k;
            v[k] = (i < SCANH_N) ? arr[i] : 0;
            s += v[k];
        }
        tmp[tx] = s;
        __syncthreads();
        for (int o = 1; o < 256; o <<= 1) {
            int t = (tx >= o) ? tmp[tx - o] : 0;
            __syncthreads();
            tmp[tx] += t;
            __syncthreads();
        }
        int excl = (tx == 0) ? 0 : tmp[tx - 1];
#pragma unroll
        for (int k = 0; k < 4; ++k) {
            int i = base + tx * 4 + k;
            if (i < SCANH_N) arr[i] = excl;
            excl += v[k];
        }
        if (tx == 255) bsum[blk] = tmp[255];
        return;
    }
    const bool user = blockIdx.x < NBLK16;
    const int blk = user ? blockIdx.x : blockIdx.x - NBLK16;
    const int K = user ? 64 : 32;
    const int kshift = user ? 6 : 5;
    const int stride = K + 8;
    const float* x = user ? xu : xi;
    const ushortT* wT = user ? wTu : wTi;
    const float* bias = user ? bu : bi;
    ushortT* out = user ? outu : outi;
    uint2* out8 = user ? out8u : out8i;
    const int rowbase = blk * 16;
    {
        int i = tx * 4;
        if (i < 16 * K) {
            const float4 v = *reinterpret_cast<const float4*>(&x[(size_t)rowbase * K + i]);
            int r = i >> kshift, c = i & (K - 1);
            uint2 w;
            w.x = pack2(v.x, v.y);
            w.y = pack2(v.z, v.w);
            *reinterpret_cast<uint2*>(&xs[r * stride + c]) = w;
        }
    }
    __syncthreads();
    const int wave = tx >> 6, lane = tx & 63;
    const int ln = lane & 15, quad = lane >> 4;
    const int n0 = wave * 32;
    floatx4 acc0 = {0.f, 0.f, 0.f, 0.f};
    floatx4 acc1 = {0.f, 0.f, 0.f, 0.f};
    for (int k0 = 0; k0 < K; k0 += 32) {
        short8 af = *reinterpret_cast<const short8*>(&xs[ln * stride + k0 + quad * 8]);
        short8 b0 = *reinterpret_cast<const short8*>(&wT[(n0 + ln) * K + k0 + quad * 8]);
        short8 b1 = *reinterpret_cast<const short8*>(&wT[(n0 + 16 + ln) * K + k0 + quad * 8]);
        acc0 = __builtin_amdgcn_mfma_f32_16x16x32_bf16(af, b0, acc0, 0, 0, 0);
        acc1 = __builtin_amdgcn_mfma_f32_16x16x32_bf16(af, b1, acc1, 0, 0, 0);
    }
    const float b0v = bias[n0 + ln], b1v = bias[n0 + 16 + ln];
#pragma unroll
    for (int r = 0; r < 4; ++r) {
        int lr = quad * 4 + r;
        int row = rowbase + lr;
        ushortT v0 = f2bf(fmaxf(acc0[r] + b0v, 0.f));
        ushortT v1 = f2bf(fmaxf(acc1[r] + b1v, 0.f));
        out[(size_t)row * H + n0 + ln] = v0;
        out[(size_t)row * H + n0 + 16 + ln] = v1;
        os[lr * 128 + n0 + ln] = v0;
        os[lr * 128 + n0 + 16 + ln] = v1;
    }
    __syncthreads();
    {   // fp8 shadow copy: 2048 elems, 8 per thread, coalesced
        int i = tx * 8;
        int r = i >> 7, c = i & 127;
        uint4 w = *reinterpret_cast<const uint4*>(&os[r * 128 + c]);
        float f[8] = {lo2f(w.x), hi2f(w.x), lo2f(w.y), hi2f(w.y),
                      lo2f(w.z), hi2f(w.z), lo2f(w.w), hi2f(w.w)};
        out8[(size_t)(rowbase + r) * 16 + (c >> 3)] = pk8(f);
    }
}

// 256-thread LDS exclusive scan of NBS raw block sums into bpre[256].
static __device__ __forceinline__ void bsum_scan(const int* __restrict__ bsum, int* bpre, int tx) {
    int v = (tx < NBS) ? bsum[tx] : 0;
    bpre[tx] = v;
    __syncthreads();
    for (int o = 1; o < 256; o <<= 1) {
        int t = (tx >= o) ? bpre[tx - o] : 0;
        __syncthreads();
        bpre[tx] += t;
        __syncthreads();
    }
    int excl = (tx == 0) ? 0 : bpre[tx - 1];
    __syncthreads();
    bpre[tx] = excl;
}

// ---------------------------------------------------------------------------
// D3: scatter packed (dst<<16 | src) into per-(bucket,chunk) exclusive ranges
// ---------------------------------------------------------------------------
__global__ void scatterA_kernel(const int* __restrict__ e0, const int* __restrict__ e1,
                                const int* __restrict__ scanH0, const int* __restrict__ bsum0,
                                const int* __restrict__ scanH1, const int* __restrict__ bsum1,
                                uintT* __restrict__ stage0, uintT* __restrict__ stage1) {
    __shared__ int cur[NBUK];
    __shared__ int bpre[256];
    const int tx = threadIdx.x;
    const bool first = blockIdx.x < BCH;
    const int c = first ? blockIdx.x : blockIdx.x - BCH;
    const int* ei = first ? e0 : e1;
    const int* scanH = first ? scanH0 : scanH1;
    const int* bsum = first ? bsum0 : bsum1;
    uintT* stage = first ? stage0 : stage1;

    bsum_scan(bsum, bpre, tx);
    __syncthreads();
    for (int i = tx; i < NBUK; i += 256) {
        int idx = i * BCH + c;
        cur[i] = scanH[idx] + bpre[idx >> 10];
    }
    __syncthreads();
    const int base = c * CHUNK;
    for (int e = tx; e < CHUNK; e += 256) {
        int s = ei[base + e];
        int d = ei[NEDGE + base + e];
        int pos = atomicAdd(&cur[d >> 6], 1);
        stage[pos] = ((uintT)d << 16) | (uintT)s;
    }
}

// ---------------------------------------------------------------------------
// D4: per-bucket local sort by dst; dense u16 srcidx + off[]
// ---------------------------------------------------------------------------
__global__ void passB_kernel(const uintT* __restrict__ stage0, const int* __restrict__ scanH0,
                             const int* __restrict__ bsum0, ushortT* __restrict__ srcidx0,
                             int* __restrict__ off0,
                             const uintT* __restrict__ stage1, const int* __restrict__ scanH1,
                             const int* __restrict__ bsum1, ushortT* __restrict__ srcidx1,
                             int* __restrict__ off1) {
    __shared__ uintT inbuf[BCAP];
    __shared__ ushortT outbuf[BCAP];
    __shared__ int hist[64], scn[64], cur[64];
    __shared__ int bpre[256];
    const int tx = threadIdx.x;
    const bool first = blockIdx.x < NBUK;
    const int b = first ? blockIdx.x : blockIdx.x - NBUK;
    const uintT* stage = first ? stage0 : stage1;
    const int* scanH = first ? scanH0 : scanH1;
    const int* bsum = first ? bsum0 : bsum1;
    ushortT* srcidx = first ? srcidx0 : srcidx1;
    int* off = first ? off0 : off1;

    bsum_scan(bsum, bpre, tx);
    __syncthreads();
    if (tx < 64) hist[tx] = 0;

    const int ib = b * BCH;
    const int base = scanH[ib] + bpre[ib >> 10];
    const int end = (b == NBUK - 1) ? NEDGE : (scanH[ib + BCH] + bpre[(ib + BCH) >> 10]);
    const int size = end - base;

    for (int i = tx; i < size; i += 256) inbuf[i] = stage[base + i];
    __syncthreads();
    for (int i = tx; i < size; i += 256) atomicAdd(&hist[(inbuf[i] >> 16) & 63], 1);
    __syncthreads();
    if (tx == 0) {
        int s = 0;
#pragma unroll
        for (int i = 0; i < 64; ++i) { scn[i] = s; s += hist[i]; }
    }
    __syncthreads();
    if (tx < 64) cur[tx] = scn[tx];
    __syncthreads();
    for (int i = tx; i < size; i += 256) {
        uintT w = inbuf[i];
        int pos = atomicAdd(&cur[(w >> 16) & 63], 1);
        outbuf[pos] = (ushortT)(w & 0xffffu);
    }
    __syncthreads();
    for (int i = tx; i < size; i += 256) srcidx[base + i] = outbuf[i];
    if (tx < 64) {
        int d = b * 64 + tx;
        if (d < NNODE) off[d] = base + scn[tx];
    }
    if (b == NBUK - 1 && tx == 64) off[NNODE] = NEDGE;
}

// ---------------------------------------------------------------------------
// D5/D7: dedicated gather-mean from FP8 source rows (128 B/row). One WAVE per
// dst row; 16-lane group g covers one row via dwordx2; one wave-load fetches
// 4 edges. Row's first 64 indices loaded once, per-chunk idx via __shfl.
// ---------------------------------------------------------------------------
__global__ void gather2_kernel(const uint2* __restrict__ src8A, const ushortT* __restrict__ srcA,
                               const int* __restrict__ offA, ushortT* __restrict__ aggA,
                               const uint2* __restrict__ src8B, const ushortT* __restrict__ srcB,
                               const int* __restrict__ offB, ushortT* __restrict__ aggB) {
    const bool first = blockIdx.x < GBLK;
    const int blk = first ? blockIdx.x : blockIdx.x - GBLK;
    const uint2* srcv = first ? src8A : src8B;
    const ushortT* srcidx = first ? srcA : srcB;
    const int* off = first ? offA : offB;
    ushortT* agg = first ? aggA : aggB;

    const int wave = threadIdx.x >> 6, lane = threadIdx.x & 63;
    const int g = lane >> 4, gl = lane & 15;
    const int row = blk * 4 + wave;
    const int start = off[row];
    const int deg = off[row + 1] - start;
    const ushortT* sidx = srcidx + start;

    const int clampi = (deg > 0) ? deg - 1 : 0;
    const int myidx = sidx[(lane < clampi) ? lane : clampi];
    const int degc = (deg < 64) ? deg : 64;

    float2v acc0 = {0.f, 0.f}, acc1 = {0.f, 0.f}, acc2 = {0.f, 0.f}, acc3 = {0.f, 0.f};
    int j = 0;
    for (; j + 16 <= degc; j += 16) {         // unmasked, idx via shuffle
        uint2 v[4];
#pragma unroll
        for (int u = 0; u < 4; ++u) {
            int s = __shfl(myidx, j + u * 4 + g, 64);
            v[u] = srcv[(size_t)s * 16 + gl];
        }
#pragma unroll
        for (int u = 0; u < 4; ++u) {
            acc0 += f8lo(v[u].x);
            acc1 += f8hi(v[u].x);
            acc2 += f8lo(v[u].y);
            acc3 += f8hi(v[u].y);
        }
    }
    if (j < degc) {                           // one masked 16-chunk, 4 loads in flight
        uint2 v[4];
        float m[4];
#pragma unroll
        for (int u = 0; u < 4; ++u) {
            int e = j + u * 4 + g;
            int ee = (e < degc) ? e : degc - 1;
            int s = __shfl(myidx, ee, 64);
            v[u] = srcv[(size_t)s * 16 + gl];
            m[u] = (e < degc) ? 1.f : 0.f;
        }
#pragma unroll
        for (int u = 0; u < 4; ++u) {
            float2v t0 = f8lo(v[u].x), t1 = f8hi(v[u].x);
            float2v t2 = f8lo(v[u].y), t3 = f8hi(v[u].y);
            acc0.x = fmaf(t0.x, m[u], acc0.x); acc0.y = fmaf(t0.y, m[u], acc0.y);
            acc1.x = fmaf(t1.x, m[u], acc1.x); acc1.y = fmaf(t1.y, m[u], acc1.y);
            acc2.x = fmaf(t2.x, m[u], acc2.x); acc2.y = fmaf(t2.y, m[u], acc2.y);
            acc3.x = fmaf(t3.x, m[u], acc3.x); acc3.y = fmaf(t3.y, m[u], acc3.y);
        }
    }
    if (deg > 64) {                           // cold path: P(deg>64) ~ 0
        for (int e0 = 64; e0 < deg; e0 += 4) {
            int e = e0 + g;
            int ec = (e < deg) ? e : deg - 1;
            int s = sidx[ec];
            uint2 v = srcv[(size_t)s * 16 + gl];
            float m = (e < deg) ? 1.f : 0.f;
            float2v t0 = f8lo(v.x), t1 = f8hi(v.x);
            float2v t2 = f8lo(v.y), t3 = f8hi(v.y);
            acc0.x = fmaf(t0.x, m, acc0.x); acc0.y = fmaf(t0.y, m, acc0.y);
            acc1.x = fmaf(t1.x, m, acc1.x); acc1.y = fmaf(t1.y, m, acc1.y);
            acc2.x = fmaf(t2.x, m, acc2.x); acc2.y = fmaf(t2.y, m, acc2.y);
            acc3.x = fmaf(t3.x, m, acc3.x); acc3.y = fmaf(t3.y, m, acc3.y);
        }
    }
#pragma unroll
    for (int o = 16; o <= 32; o <<= 1) {
        acc0.x += __shfl_xor(acc0.x, o, 64); acc0.y += __shfl_xor(acc0.y, o, 64);
        acc1.x += __shfl_xor(acc1.x, o, 64); acc1.y += __shfl_xor(acc1.y, o, 64);
        acc2.x += __shfl_xor(acc2.x, o, 64); acc2.y += __shfl_xor(acc2.y, o, 64);
        acc3.x += __shfl_xor(acc3.x, o, 64); acc3.y += __shfl_xor(acc3.y, o, 64);
    }
    if (lane < 16) {
        const float inv = 1.f / fmaxf((float)deg, 1.f);
        uint4 o;
        o.x = pack2(acc0.x * inv, acc0.y * inv);
        o.y = pack2(acc1.x * inv, acc1.y * inv);
        o.z = pack2(acc2.x * inv, acc2.y * inv);
        o.w = pack2(acc3.x * inv, acc3.y * inv);
        ((uint4*)agg)[(size_t)row * 16 + gl] = o;
    }
}

// ---------------------------------------------------------------------------
// D6: streaming SAGE MFMA, 64 rows/block, B fragments in registers.
//   out = relu( l2norm( [agg | xdst] @ [wl;wr] + bl ) ) + xdst
// out / out8 are NULLABLE (dead outputs skipped): L0 A-half writes only fp8
// (hi8B, L1 gather source); L0 B-half writes only bf16 (huB, L1 xdst).
// ---------------------------------------------------------------------------
__global__ void sageM_kernel(
    const ushortT* __restrict__ aggA, const ushortT* __restrict__ xdstA,
    const ushortT* __restrict__ wlTA, const float* __restrict__ blA,
    const ushortT* __restrict__ wrTA, ushortT* __restrict__ outA, uint2* __restrict__ out8A,
    const ushortT* __restrict__ aggB, const ushortT* __restrict__ xdstB,
    const ushortT* __restrict__ wlTB, const float* __restrict__ blB,
    const ushortT* __restrict__ wrTB, ushortT* __restrict__ outB, uint2* __restrict__ out8B) {
    __shared__ __align__(16) ushortT At[64 * 264];     // 33.8 KB
    __shared__ float part[4][64];
    __shared__ float scl[64];
    const bool first = blockIdx.x < SAGEB;
    const int blk = first ? blockIdx.x : blockIdx.x - SAGEB;
    const ushortT* agg  = first ? aggA  : aggB;
    const ushortT* xdst = first ? xdstA : xdstB;
    const ushortT* wlT  = first ? wlTA  : wlTB;
    const float* bl     = first ? blA   : blB;
    const ushortT* wrT  = first ? wrTA  : wrTB;
    ushortT* out        = first ? outA  : outB;
    uint2* out8         = first ? out8A : out8B;

    const int tx = threadIdx.x;
    const int rowbase = blk * 64;
    const int wave = tx >> 6, lane = tx & 63;
    const int ln = lane & 15, quad = lane >> 4;
    const int n0 = wave * 32;

#pragma unroll
    for (int it = 0; it < 4; ++it) {
        int i = it * 256 + tx;
        int r = i >> 4, ch = i & 15;
        int row = rowbase + r;
        size_t rs = (size_t)((row < NNODE) ? row : NNODE - 1) * H + ch * 8;
        *reinterpret_cast<short8*>(&At[r * 264 + ch * 8]) =
            *reinterpret_cast<const short8*>(&agg[rs]);
        *reinterpret_cast<short8*>(&At[r * 264 + 128 + ch * 8]) =
            *reinterpret_cast<const short8*>(&xdst[rs]);
    }

    short8 bf[8][2];
#pragma unroll
    for (int kt = 0; kt < 8; ++kt) {
        const ushortT* wT = (kt < 4) ? wlT : wrT;
        const int kk = (kt & 3) * 32 + quad * 8;
        bf[kt][0] = *reinterpret_cast<const short8*>(&wT[(n0 + ln) * 128 + kk]);
        bf[kt][1] = *reinterpret_cast<const short8*>(&wT[(n0 + 16 + ln) * 128 + kk]);
    }
    __syncthreads();

    floatx4 acc[4][2] = {};
#pragma unroll
    for (int ms = 0; ms < 4; ++ms) {
#pragma unroll
        for (int kt = 0; kt < 8; ++kt) {
            short8 af = *reinterpret_cast<const short8*>(
                &At[(ms * 16 + ln) * 264 + kt * 32 + quad * 8]);
            acc[ms][0] = __builtin_amdgcn_mfma_f32_16x16x32_bf16(af, bf[kt][0], acc[ms][0], 0, 0, 0);
            acc[ms][1] = __builtin_amdgcn_mfma_f32_16x16x32_bf16(af, bf[kt][1], acc[ms][1], 0, 0, 0);
        }
    }

    const float bl0 = bl[n0 + ln];
    const float bl1 = bl[n0 + 16 + ln];
#pragma unroll
    for (int ms = 0; ms < 4; ++ms) {
#pragma unroll
        for (int r = 0; r < 4; ++r) {
            float v0 = acc[ms][0][r] + bl0;
            float v1 = acc[ms][1][r] + bl1;
            acc[ms][0][r] = v0;
            acc[ms][1][r] = v1;
            float s = v0 * v0 + v1 * v1;
            s += __shfl_xor(s, 1, 64);
            s += __shfl_xor(s, 2, 64);
            s += __shfl_xor(s, 4, 64);
            s += __shfl_xor(s, 8, 64);
            if (ln == 0) part[wave][ms * 16 + quad * 4 + r] = s;
        }
    }
    __syncthreads();
    if (tx < 64) {
        float t = part[0][tx] + part[1][tx] + part[2][tx] + part[3][tx];
        scl[tx] = 1.f / fmaxf(sqrtf(t), 1e-12f);
    }
    __syncthreads();
#pragma unroll
    for (int ms = 0; ms < 4; ++ms) {
#pragma unroll
        for (int r = 0; r < 4; ++r) {
            const int lr = ms * 16 + quad * 4 + r;
            const int row = rowbase + lr;
            const float sc = scl[lr];
            float o0 = fmaxf(acc[ms][0][r] * sc, 0.f) + bf2f(At[lr * 264 + 128 + n0 + ln]);
            float o1 = fmaxf(acc[ms][1][r] * sc, 0.f) + bf2f(At[lr * 264 + 128 + n0 + 16 + ln]);
            ushortT b0 = f2bf(o0), b1 = f2bf(o1);
            if (out && row < NNODE) {
                out[(size_t)row * H + n0 + ln] = b0;
                out[(size_t)row * H + n0 + 16 + ln] = b1;
            }
            if (out8) {
                At[lr * 264 + n0 + ln] = b0;
                At[lr * 264 + n0 + 16 + ln] = b1;
            }
        }
    }
    if (out8) {
        __syncthreads();
#pragma unroll
        for (int it = 0; it < 4; ++it) {
            int i = it * 2048 + tx * 8;
            int r = i >> 7, c = i & 127;
            int row = rowbase + r;
            if (row < NNODE) {
                uint4 w = *reinterpret_cast<const uint4*>(&At[r * 264 + c]);
                float f[8] = {lo2f(w.x), hi2f(w.x), lo2f(w.y), hi2f(w.y),
                              lo2f(w.z), hi2f(w.z), lo2f(w.w), hi2f(w.w)};
                out8[(size_t)row * 16 + (c >> 3)] = pk8(f);
            }
        }
    }
}

// ---------------------------------------------------------------------------
// D8: fused layer-1 user-SAGE + head (the layer-1 item update is DEAD code —
// head consumes hu only). Computes new_hu rows for this 64-row tile entirely
// in registers/LDS, then z = relu(hu @ w1 + b1), out = z @ w2 + b2.
// No hu global round-trip at all.
// ---------------------------------------------------------------------------
__global__ void sageH_kernel(
    const ushortT* __restrict__ agg, const ushortT* __restrict__ xdst,
    const ushortT* __restrict__ wlT, const float* __restrict__ bl,
    const ushortT* __restrict__ wrT,
    const ushortT* __restrict__ w1T, const float* __restrict__ b1,
    const float* __restrict__ w2, const float* __restrict__ b2,
    float* __restrict__ out) {
    __shared__ __align__(16) ushortT At[64 * 264];     // 33.8 KB (zs overlaid later)
    __shared__ float part[4][64];
    __shared__ float scl[64];
    const int tx = threadIdx.x;
    const int blk = blockIdx.x;
    const int rowbase = blk * 64;
    const int wave = tx >> 6, lane = tx & 63;
    const int ln = lane & 15, quad = lane >> 4;
    const int n0 = wave * 32;

#pragma unroll
    for (int it = 0; it < 4; ++it) {
        int i = it * 256 + tx;
        int r = i >> 4, ch = i & 15;
        int row = rowbase + r;
        size_t rs = (size_t)((row < NNODE) ? row : NNODE - 1) * H + ch * 8;
        *reinterpret_cast<short8*>(&At[r * 264 + ch * 8]) =
            *reinterpret_cast<const short8*>(&agg[rs]);
        *reinterpret_cast<short8*>(&At[r * 264 + 128 + ch * 8]) =
            *reinterpret_cast<const short8*>(&xdst[rs]);
    }

    short8 bf[8][2];
#pragma unroll
    for (int kt = 0; kt < 8; ++kt) {
        const ushortT* wT = (kt < 4) ? wlT : wrT;
        const int kk = (kt & 3) * 32 + quad * 8;
        bf[kt][0] = *reinterpret_cast<const short8*>(&wT[(n0 + ln) * 128 + kk]);
        bf[kt][1] = *reinterpret_cast<const short8*>(&wT[(n0 + 16 + ln) * 128 + kk]);
    }
    __syncthreads();

    floatx4 acc[4][2] = {};
#pragma unroll
    for (int ms = 0; ms < 4; ++ms) {
#pragma unroll
        for (int kt = 0; kt < 8; ++kt) {
            short8 af = *reinterpret_cast<const short8*>(
                &At[(ms * 16 + ln) * 264 + kt * 32 + quad * 8]);
            acc[ms][0] = __builtin_amdgcn_mfma_f32_16x16x32_bf16(af, bf[kt][0], acc[ms][0], 0, 0, 0);
            acc[ms][1] = __builtin_amdgcn_mfma_f32_16x16x32_bf16(af, bf[kt][1], acc[ms][1], 0, 0, 0);
        }
    }

    const float bl0 = bl[n0 + ln];
    const float bl1 = bl[n0 + 16 + ln];
#pragma unroll
    for (int ms = 0; ms < 4; ++ms) {
#pragma unroll
        for (int r = 0; r < 4; ++r) {
            float v0 = acc[ms][0][r] + bl0;
            float v1 = acc[ms][1][r] + bl1;
            acc[ms][0][r] = v0;
            acc[ms][1][r] = v1;
            float s = v0 * v0 + v1 * v1;
            s += __shfl_xor(s, 1, 64);
            s += __shfl_xor(s, 2, 64);
            s += __shfl_xor(s, 4, 64);
            s += __shfl_xor(s, 8, 64);
            if (ln == 0) part[wave][ms * 16 + quad * 4 + r] = s;
        }
    }
    __syncthreads();
    if (tx < 64) {
        float t = part[0][tx] + part[1][tx] + part[2][tx] + part[3][tx];
        scl[tx] = 1.f / fmaxf(sqrtf(t), 1e-12f);
    }
    __syncthreads();
    // new_hu rows -> At agg half (bf16), consumed by head MFMA
#pragma unroll
    for (int ms = 0; ms < 4; ++ms) {
#pragma unroll
        for (int r = 0; r < 4; ++r) {
            const int lr = ms * 16 + quad * 4 + r;
            const float sc = scl[lr];
            float o0 = fmaxf(acc[ms][0][r] * sc, 0.f) + bf2f(At[lr * 264 + 128 + n0 + ln]);
            float o1 = fmaxf(acc[ms][1][r] * sc, 0.f) + bf2f(At[lr * 264 + 128 + n0 + 16 + ln]);
            At[lr * 264 + n0 + ln] = f2bf(o0);
            At[lr * 264 + n0 + 16 + ln] = f2bf(o1);
        }
    }
    __syncthreads();

    // head GEMM1: z = relu(hu @ w1 + b1); w1 frags in registers
    short8 wf[4];
#pragma unroll
    for (int kt = 0; kt < 4; ++kt)
        wf[kt] = *reinterpret_cast<const short8*>(&w1T[(wave * 16 + ln) * 128 + kt * 32 + quad * 8]);
    floatx4 ah[4] = {};
#pragma unroll
    for (int ms = 0; ms < 4; ++ms) {
#pragma unroll
        for (int kt = 0; kt < 4; ++kt) {
            short8 af = *reinterpret_cast<const short8*>(
                &At[(ms * 16 + ln) * 264 + kt * 32 + quad * 8]);
            ah[ms] = __builtin_amdgcn_mfma_f32_16x16x32_bf16(af, wf[kt], ah[ms], 0, 0, 0);
        }
    }
    __syncthreads();                        // all At reads done; overlay zs
    float* zs = (float*)At;                 // [64][72] = 18.4 KB < 33.8 KB
    const float bv = b1[wave * 16 + ln];
#pragma unroll
    for (int ms = 0; ms < 4; ++ms)
#pragma unroll
        for (int r = 0; r < 4; ++r)
            zs[(ms * 16 + quad * 4 + r) * 72 + wave * 16 + ln] = fmaxf(ah[ms][r] + bv, 0.f);
    __syncthreads();
    // head GEMM2: 64 rows x 8 cols, 2 outputs per thread
#pragma unroll
    for (int u = 0; u < 2; ++u) {
        int i = tx * 2 + u;
        int r = i >> 3, c = i & 7;
        int row = rowbase + r;
        if (row < NNODE) {
            float a = b2[c];
#pragma unroll 8
            for (int k = 0; k < 64; ++k) a += zs[r * 72 + k] * w2[k * 8 + c];
            out[(size_t)row * 8 + c] = a;
        }
    }
}

// ---------------------------------------------------------------------------
extern "C" void kernel_launch(void* const* d_in, const int* in_sizes, int n_in,
                              void* d_out, int out_size, void* d_ws, size_t ws_size,
                              hipStream_t stream) {
    const float* x_user     = (const float*)d_in[0];
    const float* x_item     = (const float*)d_in[1];
    const int*   ei_u2i     = (const int*)d_in[2];
    const int*   ei_i2u     = (const int*)d_in[3];
    const float* enc_user_w = (const float*)d_in[4];
    const float* enc_user_b = (const float*)d_in[5];
    const float* enc_item_w = (const float*)d_in[6];
    const float* enc_item_b = (const float*)d_in[7];
    const float* W[12];
    for (int i = 0; i < 12; ++i) W[i] = (const float*)d_in[8 + i];
    const float* head_w1 = (const float*)d_in[20];
    const float* head_b1 = (const float*)d_in[21];
    const float* head_w2 = (const float*)d_in[22];
    const float* head_b2 = (const float*)d_in[23];
    float* out = (float*)d_out;

    const size_t S = (size_t)NNODE * H;
    ushortT* huA  = (ushortT*)d_ws;
    ushortT* huB  = huA + S;
    ushortT* hiA  = huB + S;
    ushortT* hiB  = hiA + S;                  // (unused now, kept for layout)
    ushortT* wT   = hiB + S;                  // 151552 bf16
    int*    scanH_i = (int*)(wT + 151552);    // [SCANH_N]
    int*    scanH_u = scanH_i + SCANH_N;
    int*    bsum_i  = scanH_u + SCANH_N;      // [256] raw block sums
    int*    bsum_u  = bsum_i + 256;
    int*    off_i   = bsum_u + 256;           // [NNODE+1]
    int*    off_u   = off_i + NNODE + 1;
    uintT*  stage_i = (uintT*)(off_u + NNODE + 1);  // [NEDGE]
    uintT*  stage_u = stage_i + NEDGE;
    ushortT* src_i  = (ushortT*)(stage_u + NEDGE);  // [NEDGE] u16
    ushortT* src_u  = src_i + NEDGE;
    ushortT* aggI   = src_u + NEDGE;          // [S]
    ushortT* aggU   = aggI + S;               // [S]
    uint2*  hu8A    = (uint2*)(aggU + S);     // fp8 shadows: NNODE*128 B each
    uint2*  hi8A    = hu8A + (size_t)NNODE * 16;
    uint2*  hi8B    = hi8A + (size_t)NNODE * 16;

    const ushortT* wTeu = wT + 131072;
    const ushortT* wTei = wT + 139264;
    const ushortT* w1T  = wT + 143360;

    // D1: weight converts + edge histograms
    setup_kernel<<<592 + 2 * BCH, 256, 0, stream>>>(
        W[0], W[2], W[3], W[5], W[6], W[8], W[9], W[11],
        enc_user_w, enc_item_w, head_w1, wT,
        ei_u2i, ei_i2u, scanH_i, scanH_u);

    // D2: encoders (bf16 + fp8 out) + scanH scans
    encscan_kernel<<<2 * NBLK16 + 2 * NBS, 256, 0, stream>>>(
        x_user, wTeu, enc_user_b, x_item, wTei, enc_item_b, huA, hiA,
        hu8A, hi8A, scanH_i, bsum_i, scanH_u, bsum_u);

    // D3/D4: locality-preserving scatter, then per-bucket sort -> CSR
    scatterA_kernel<<<2 * BCH, 256, 0, stream>>>(ei_u2i, ei_i2u, scanH_i, bsum_i,
                                                 scanH_u, bsum_u, stage_i, stage_u);
    passB_kernel<<<2 * NBUK, 256, 0, stream>>>(stage_i, scanH_i, bsum_i, src_i, off_i,
                                               stage_u, scanH_u, bsum_u, src_u, off_u);

    // layer 0: both directions
    gather2_kernel<<<2 * GBLK, 256, 0, stream>>>(hu8A, src_i, off_i, aggI,
                                                 hi8A, src_u, off_u, aggU);
    // A-half (items): only the fp8 shadow hi8B survives (L1 gather source).
    // B-half (users): only bf16 huB survives (L1 xdst).
    sageM_kernel<<<2 * SAGEB, 256, 0, stream>>>(
        aggI, hiA, wT + 0 * 16384, W[1], wT + 1 * 16384, nullptr, hi8B,
        aggU, huA, wT + 2 * 16384, W[4], wT + 3 * 16384, huB, nullptr);

    // layer 1: user direction ONLY (item update is dead code)
    gather2_kernel<<<GBLK, 256, 0, stream>>>(hi8B, src_u, off_u, aggU,
                                             hi8B, src_u, off_u, aggU);
    // fused layer-1 user-SAGE + head
    sageH_kernel<<<SAGEB, 256, 0, stream>>>(
        aggU, huB, wT + 6 * 16384, W[10], wT + 7 * 16384,
        w1T, head_b1, head_w2, head_b2, out);
}